// Round 1
// baseline (1253.014 us; speedup 1.0000x reference)
//
#include <hip/hip_runtime.h>
#include <hip/hip_bf16.h>

// LRUModel: B=8,S=2048,D=256,V=6, 4 blocks of [linear-RNN scan -> 2x(Linear+BN+gelu+res)]
// Round 0: all-f32 correctness baseline.
//   - scan parallelized 3-level: L1=32 chunks (512 rows), level2 8x8, powers Wh^32/Wh^256
//   - scan kernel: Wh column resident in 128 VGPRs per thread (512-thr wg, e-split halves)
//   - f32 tiled GEMMs for input-drive / MLP / matrix squarings
//   - BN stats: per-column atomics + fused bn/gelu/residual elementwise

#define DD 256
#define NTOT 16384  // B*S
#define L1C 32      // level-1 chunk length
#define C1C 64      // chunks per sequence
#define EPSV 1e-5f

// ws layout (float offsets)
#define OFF_U    0L
#define OFF_H    4194304L
#define OFF_E1   8388608L   // 512*256  level-1 local ends
#define OFF_EE1  8519680L   // 512*256  true level-1 ends
#define OFF_E2   8650752L   // 64*256   level-2 local ends
#define OFF_EE2  8667136L   // 64*256   true level-2 ends
#define OFF_ST   8683520L   // 512 stats
#define OFF_POW  8684032L   // 8 * 65536 power slabs

__device__ __forceinline__ float gelu_tanh(float x) {
  float x3 = x * x * x;
  float t = tanhf(0.7978845608028654f * (x + 0.044715f * x3));
  return 0.5f * x * (1.0f + t);
}

// ---------------- generic 64x64-tile f32 GEMM: C = A[N][256] @ W[256][256] (+bias) ---------
__device__ __forceinline__ void mm_tile(const float* __restrict__ A,
                                        const float* __restrict__ W,
                                        const float* __restrict__ bias,
                                        float* __restrict__ C) {
  __shared__ float As[16][68];
  __shared__ float Bs[16][68];
  const int tid = threadIdx.x;
  const int tx = tid & 15;
  const int ty = tid >> 4;
  const long bm = (long)blockIdx.x * 64;
  const int bn = blockIdx.y * 64;
  float acc[4][4] = {};
  for (int k0 = 0; k0 < 256; k0 += 16) {
    {
      const int m = tid >> 2, ks = (tid & 3) * 4;
      const float4 av = *(const float4*)(A + (bm + m) * 256 + k0 + ks);
      As[ks + 0][m] = av.x; As[ks + 1][m] = av.y;
      As[ks + 2][m] = av.z; As[ks + 3][m] = av.w;
    }
    {
      const int kk = tid >> 4, n4 = (tid & 15) * 4;
      const float4 wv = *(const float4*)(W + (k0 + kk) * 256 + bn + n4);
      Bs[kk][n4 + 0] = wv.x; Bs[kk][n4 + 1] = wv.y;
      Bs[kk][n4 + 2] = wv.z; Bs[kk][n4 + 3] = wv.w;
    }
    __syncthreads();
#pragma unroll
    for (int kk = 0; kk < 16; ++kk) {
      const float a0 = As[kk][ty * 4 + 0];
      const float a1 = As[kk][ty * 4 + 1];
      const float a2 = As[kk][ty * 4 + 2];
      const float a3 = As[kk][ty * 4 + 3];
      const float4 b = *(const float4*)(&Bs[kk][tx * 4]);
      acc[0][0] = fmaf(a0, b.x, acc[0][0]); acc[0][1] = fmaf(a0, b.y, acc[0][1]);
      acc[0][2] = fmaf(a0, b.z, acc[0][2]); acc[0][3] = fmaf(a0, b.w, acc[0][3]);
      acc[1][0] = fmaf(a1, b.x, acc[1][0]); acc[1][1] = fmaf(a1, b.y, acc[1][1]);
      acc[1][2] = fmaf(a1, b.z, acc[1][2]); acc[1][3] = fmaf(a1, b.w, acc[1][3]);
      acc[2][0] = fmaf(a2, b.x, acc[2][0]); acc[2][1] = fmaf(a2, b.y, acc[2][1]);
      acc[2][2] = fmaf(a2, b.z, acc[2][2]); acc[2][3] = fmaf(a2, b.w, acc[2][3]);
      acc[3][0] = fmaf(a3, b.x, acc[3][0]); acc[3][1] = fmaf(a3, b.y, acc[3][1]);
      acc[3][2] = fmaf(a3, b.z, acc[3][2]); acc[3][3] = fmaf(a3, b.w, acc[3][3]);
    }
    __syncthreads();
  }
  float4 bv = make_float4(0.f, 0.f, 0.f, 0.f);
  if (bias) bv = *(const float4*)(bias + bn + tx * 4);
#pragma unroll
  for (int i = 0; i < 4; ++i) {
    float4 o;
    o.x = acc[i][0] + bv.x; o.y = acc[i][1] + bv.y;
    o.z = acc[i][2] + bv.z; o.w = acc[i][3] + bv.w;
    *(float4*)(C + (bm + ty * 4 + i) * 256 + bn + tx * 4) = o;
  }
}

__global__ __launch_bounds__(256, 4) void k_mm(const float* __restrict__ A,
                                               const float* __restrict__ W,
                                               const float* __restrict__ bias,
                                               float* __restrict__ C) {
  mm_tile(A, W, bias, C);
}

// batched squaring: C = A@A for two matrices (z selects)
__global__ __launch_bounds__(256, 4) void k_sq(const float* __restrict__ A0,
                                               const float* __restrict__ A1,
                                               float* __restrict__ C0,
                                               float* __restrict__ C1) {
  const float* A = blockIdx.z ? A1 : A0;
  float* C = blockIdx.z ? C1 : C0;
  mm_tile(A, A, nullptr, C);
}

// ---------------- embedding (one-hot @ Wi0 + bi0) ----------------
__global__ void k_embed(const int* __restrict__ x, const float* __restrict__ Wi,
                        const float* __restrict__ bi, float* __restrict__ u) {
  const int n = blockIdx.x;
  const int d = threadIdx.x;
  const int t = x[n];
  u[(long)n * DD + d] = Wi[t * DD + d] + bi[d];
}

// ---------------- chunked linear-recurrence scan -----------------
// rows processed G=2 per block of 512 threads; thread (d, half) keeps W[e in half-range][d]
// in 128 VGPRs. h_new[d] = sum_e h[e]*W[e][d] + u[t][d].
__global__ __launch_bounds__(512, 2) void k_scan(const float* __restrict__ u,
                                                 const float* __restrict__ W,
                                                 const float* __restrict__ Einit,
                                                 float* __restrict__ out_full,
                                                 float* __restrict__ out_ends,
                                                 int steps, int cper) {
  const int d = threadIdx.x & 255;
  const int half = threadIdx.x >> 8;
  const long r0 = (long)blockIdx.x * 2;
  __shared__ __align__(16) float hbuf[2][DD];
  __shared__ __align__(16) float psum[2][DD];

  float w[128];
  {
    const float* Wc = W + (long)(half * 128) * DD + d;
#pragma unroll
    for (int i = 0; i < 128; ++i) w[i] = Wc[(long)i * DD];
  }

  if (half == 0) {
#pragma unroll
    for (int g = 0; g < 2; ++g) {
      const long r = r0 + g;
      float hv = 0.f;
      if (Einit != nullptr && (int)(r % cper) != 0) hv = Einit[(r - 1) * DD + d];
      hbuf[g][d] = hv;
    }
  }
  __syncthreads();

  const float* __restrict__ ur0 = u + r0 * steps * DD + d;
  const float* __restrict__ ur1 = ur0 + (long)steps * DD;
  float* of0 = out_full ? out_full + r0 * steps * DD + d : nullptr;
  float* of1 = of0 ? of0 + (long)steps * DD : nullptr;
  const int e0 = half * 128;

  for (int t = 0; t < steps; ++t) {
    float uv0 = 0.f, uv1 = 0.f;
    if (half == 0) { uv0 = ur0[(long)t * DD]; uv1 = ur1[(long)t * DD]; }
    float a00 = 0.f, a01 = 0.f, a10 = 0.f, a11 = 0.f;
    const float4* hb0 = (const float4*)(&hbuf[0][e0]);
    const float4* hb1 = (const float4*)(&hbuf[1][e0]);
#pragma unroll
    for (int i = 0; i < 32; ++i) {
      const float4 h0 = hb0[i];
      const float4 h1 = hb1[i];
      a00 = fmaf(h0.x, w[4 * i + 0], a00);
      a01 = fmaf(h0.y, w[4 * i + 1], a01);
      a00 = fmaf(h0.z, w[4 * i + 2], a00);
      a01 = fmaf(h0.w, w[4 * i + 3], a01);
      a10 = fmaf(h1.x, w[4 * i + 0], a10);
      a11 = fmaf(h1.y, w[4 * i + 1], a11);
      a10 = fmaf(h1.z, w[4 * i + 2], a10);
      a11 = fmaf(h1.w, w[4 * i + 3], a11);
    }
    const float p0 = a00 + a01;
    const float p1 = a10 + a11;
    __syncthreads();
    if (half == 1) { psum[0][d] = p0; psum[1][d] = p1; }
    __syncthreads();
    if (half == 0) {
      const float n0 = p0 + psum[0][d] + uv0;
      const float n1 = p1 + psum[1][d] + uv1;
      hbuf[0][d] = n0; hbuf[1][d] = n1;
      if (of0) { of0[(long)t * DD] = n0; of1[(long)t * DD] = n1; }
    }
    __syncthreads();
  }
  if (out_ends != nullptr && half == 0) {
    out_ends[r0 * DD + d] = hbuf[0][d];
    out_ends[(r0 + 1) * DD + d] = hbuf[1][d];
  }
}

// ---------------- BN stats (per-column sum & sumsq via atomics) --------------
__global__ __launch_bounds__(256) void k_colstats(const float* __restrict__ y,
                                                  float* __restrict__ stats) {
  const int d = threadIdx.x;
  const long base = (long)blockIdx.x * 128 * DD;
  float s = 0.f, s2 = 0.f;
  for (int r = 0; r < 128; ++r) {
    const float v = y[base + (long)r * DD + d];
    s += v;
    s2 = fmaf(v, v, s2);
  }
  atomicAdd(&stats[d], s);
  atomicAdd(&stats[DD + d], s2);
}

// ---------------- fused bn + gelu + residual (in-place on x) -----------------
__global__ __launch_bounds__(256) void k_bngelu(const float* __restrict__ y,
                                                const float* __restrict__ stats,
                                                const float* __restrict__ scale,
                                                const float* __restrict__ bias,
                                                float* __restrict__ x) {
  const long i4 = ((long)blockIdx.x * 256 + threadIdx.x) * 4;
  const int d = (int)(i4 & 255);
  const float4 yv = *(const float4*)(y + i4);
  const float4 xv = *(const float4*)(x + i4);
  const float4 sm = *(const float4*)(stats + d);
  const float4 sq = *(const float4*)(stats + DD + d);
  const float4 sc = *(const float4*)(scale + d);
  const float4 bi = *(const float4*)(bias + d);
  float4 o;
  {
    const float mu = sm.x * (1.f / NTOT);
    const float var = sq.x * (1.f / NTOT) - mu * mu;
    const float a = sc.x * rsqrtf(var + EPSV);
    o.x = gelu_tanh((yv.x - mu) * a + bi.x) + xv.x;
  }
  {
    const float mu = sm.y * (1.f / NTOT);
    const float var = sq.y * (1.f / NTOT) - mu * mu;
    const float a = sc.y * rsqrtf(var + EPSV);
    o.y = gelu_tanh((yv.y - mu) * a + bi.y) + xv.y;
  }
  {
    const float mu = sm.z * (1.f / NTOT);
    const float var = sq.z * (1.f / NTOT) - mu * mu;
    const float a = sc.z * rsqrtf(var + EPSV);
    o.z = gelu_tanh((yv.z - mu) * a + bi.z) + xv.z;
  }
  {
    const float mu = sm.w * (1.f / NTOT);
    const float var = sq.w * (1.f / NTOT) - mu * mu;
    const float a = sc.w * rsqrtf(var + EPSV);
    o.w = gelu_tanh((yv.w - mu) * a + bi.w) + xv.w;
  }
  *(float4*)(x + i4) = o;
}

// ---------------- final logits: out[n][v] = h[n]:256 . Wr[:,v] + br[v] -------
__global__ __launch_bounds__(256) void k_logits(const float* __restrict__ h,
                                                const float* __restrict__ Wr,
                                                const float* __restrict__ br,
                                                float* __restrict__ out) {
  const long i = (long)blockIdx.x * 256 + threadIdx.x;  // over 16384*6
  const int n = (int)(i / 6);
  const int v = (int)(i % 6);
  const float* hr = h + (long)n * DD;
  float acc0 = br[v], acc1 = 0.f;
#pragma unroll 8
  for (int dd = 0; dd < 256; dd += 2) {
    acc0 = fmaf(hr[dd], Wr[dd * 6 + v], acc0);
    acc1 = fmaf(hr[dd + 1], Wr[(dd + 1) * 6 + v], acc1);
  }
  out[i] = acc0 + acc1;
}

extern "C" void kernel_launch(void* const* d_in, const int* in_sizes, int n_in,
                              void* d_out, int out_size, void* d_ws, size_t ws_size,
                              hipStream_t stream) {
  const int* x = (const int*)d_in[0];
  const float* Wi0 = (const float*)d_in[1];
  const float* bi0 = (const float*)d_in[2];
  const float* Wh0 = (const float*)d_in[3];
  const float* m0W = (const float*)d_in[4];
  const float* m0b = (const float*)d_in[5];
  const float* m0s = (const float*)d_in[6];
  const float* m0bi = (const float*)d_in[7];
  const float* Wi1 = (const float*)d_in[8];
  const float* bi1 = (const float*)d_in[9];
  const float* Wh1 = (const float*)d_in[10];
  const float* m1W = (const float*)d_in[11];
  const float* m1b = (const float*)d_in[12];
  const float* m1s = (const float*)d_in[13];
  const float* m1bi = (const float*)d_in[14];
  const float* Wr = (const float*)d_in[15];
  const float* br = (const float*)d_in[16];

  float* ws = (float*)d_ws;
  float* u = ws + OFF_U;     // also reused as y in MLP
  float* h = ws + OFF_H;
  float* e1 = ws + OFF_E1;
  float* ee1 = ws + OFF_EE1;
  float* e2 = ws + OFF_E2;
  float* ee2 = ws + OFF_EE2;
  float* stats = ws + OFF_ST;
  float* pw = ws + OFF_POW;
  float* t0 = pw;                 // t0[2]
  float* t1 = pw + 131072;        // t1[2]
  float* P32 = pw + 262144;       // P32[2]
  float* P256 = pw + 393216;      // P256[2]

  const dim3 mmGrid(NTOT / 64, 4);
  const dim3 sqGrid(4, 4, 2);

  // matrix powers: Wh^2..Wh^32 and Wh^256, for both Wh0 and Wh1
  k_sq<<<sqGrid, 256, 0, stream>>>(Wh0, Wh1, t0, t0 + 65536);          // ^2
  k_sq<<<sqGrid, 256, 0, stream>>>(t0, t0 + 65536, t1, t1 + 65536);    // ^4
  k_sq<<<sqGrid, 256, 0, stream>>>(t1, t1 + 65536, t0, t0 + 65536);    // ^8
  k_sq<<<sqGrid, 256, 0, stream>>>(t0, t0 + 65536, t1, t1 + 65536);    // ^16
  k_sq<<<sqGrid, 256, 0, stream>>>(t1, t1 + 65536, P32, P32 + 65536);  // ^32
  k_sq<<<sqGrid, 256, 0, stream>>>(P32, P32 + 65536, t0, t0 + 65536);  // ^64
  k_sq<<<sqGrid, 256, 0, stream>>>(t0, t0 + 65536, t1, t1 + 65536);    // ^128
  k_sq<<<sqGrid, 256, 0, stream>>>(t1, t1 + 65536, P256, P256 + 65536);// ^256

  for (int blk = 0; blk < 4; ++blk) {
    const int pi = blk ? 1 : 0;
    const float* Wh = pi ? Wh1 : Wh0;
    const float* P32p = P32 + pi * 65536;
    const float* P256p = P256 + pi * 65536;
    const float* mW = pi ? m1W : m0W;
    const float* mb = pi ? m1b : m0b;
    const float* msc = pi ? m1s : m0s;
    const float* mbi = pi ? m1bi : m0bi;

    // input drive u
    if (blk == 0) {
      k_embed<<<NTOT, 256, 0, stream>>>(x, Wi0, bi0, u);
    } else {
      k_mm<<<mmGrid, 256, 0, stream>>>(h, Wi1, bi1, u);
    }

    // 3-level chunked scan
    k_scan<<<256, 512, 0, stream>>>(u, Wh, nullptr, nullptr, e1, L1C, 1);      // local pass1
    k_scan<<<32, 512, 0, stream>>>(e1, P32p, nullptr, nullptr, e2, 8, 1);      // lvl2 pass1
    k_scan<<<4, 512, 0, stream>>>(e2, P256p, nullptr, ee2, nullptr, 8, 1);     // lvl3 full
    k_scan<<<32, 512, 0, stream>>>(e1, P32p, ee2, ee1, nullptr, 8, 8);         // lvl2 pass2
    k_scan<<<256, 512, 0, stream>>>(u, Wh, ee1, h, nullptr, L1C, C1C);         // local pass2

    // MLP: 2x (Linear -> BN -> gelu -> +res), y reuses u buffer
    for (int l = 0; l < 2; ++l) {
      k_mm<<<mmGrid, 256, 0, stream>>>(h, mW + l * 65536, mb + l * 256, u);
      hipMemsetAsync(stats, 0, 512 * sizeof(float), stream);
      k_colstats<<<128, 256, 0, stream>>>(u, stats);
      k_bngelu<<<NTOT * DD / 1024, 256, 0, stream>>>(u, stats, msc + l * 256,
                                                     mbi + l * 256, h);
    }
  }

  k_logits<<<NTOT * 6 / 256, 256, 0, stream>>>(h, Wr, br, (float*)d_out);
}

// Round 5
// 951.930 us; speedup vs baseline: 1.3163x; 1.3163x over previous
//
#include <hip/hip_runtime.h>
#include <hip/hip_bf16.h>

// LRUModel r3 (resubmit after infra timeout): r2 + one-line fix in k_castT dst
// indexing (m1W slabs were landing in wrong WtT slots; slot 4 stayed
// 0xAA-poisoned -> absmax 8.33).
// B=8,S=2048,D=256,V=6, 4 blocks of [linear-RNN scan -> 2x(Linear+BN+gelu+res)]
//  - L1 chunk=16: pass1 local scan (f32 VALU) -> h_local + E1 ends
//  - lvl2/lvl3 small f32 scans -> true chunk inits EE1
//  - correction: h += init_c @ Wh^{j+1}, batched bf16 MFMA GEMM over j (grid.z)
//  - MLP/u-drive GEMMs: bf16 MFMA, col-stats fused in epilogue (shfl+atomics)
//  - logits: MFMA with N padded 6->16

#define DD 256
#define NTOT 16384
#define L1C 16
#define EPSV 1e-5f

typedef unsigned short ushort_t;
typedef __attribute__((ext_vector_type(8))) unsigned short ushort8;
typedef __attribute__((ext_vector_type(8))) __bf16 bf16x8;
typedef __attribute__((ext_vector_type(4))) float f32x4;

// ws layout (float offsets)
#define OFF_U     0L
#define OFF_H     4194304L
#define OFF_E1    8388608L    // 1024*256
#define OFF_EE1   8650752L    // 1024*256
#define OFF_E2    8912896L    // 64*256
#define OFF_T2    8929280L    // 64*256
#define OFF_ST    8945664L    // 8*512 stats slabs
#define OFF_SLABF 8949760L    // 2*16*65536 f32 power slab Wh^1..Wh^16
#define OFF_P256F 11046912L   // 2*65536
#define OFF_TA    11177984L   // 2*65536
#define OFF_TB    11309056L   // 2*65536
#define OFF_SLABT 11440128L   // 2*16*65536 ushort (bf16 transposed slab)
#define OFF_WTT   12488704L   // 5*65536 ushort (Wi1,m0W0,m0W1,m1W0,m1W1 bf16 T)

__device__ __forceinline__ ushort_t bfc(float f) {
  unsigned u = __builtin_bit_cast(unsigned, f);
  unsigned r = (u + 0x7FFFu + ((u >> 16) & 1u)) >> 16;
  return (ushort_t)r;
}

__device__ __forceinline__ bf16x8 ldsbf(const ushort_t* p, int idx) {
  return __builtin_bit_cast(bf16x8, *(const ushort8*)(p + idx));
}

__device__ __forceinline__ f32x4 mfma16(bf16x8 a, bf16x8 b, f32x4 c) {
  return __builtin_amdgcn_mfma_f32_16x16x32_bf16(a, b, c, 0, 0, 0);
}

__device__ __forceinline__ float gelu_fast(float x) {
  const float z = 0.7978845608028654f * (x + 0.044715f * x * x * x);
  return x / (1.f + __expf(-2.f * z));  // x * sigmoid(2z) == 0.5x(1+tanh z)
}

// ---------------- f32 64x64-tile GEMM (power-slab construction only) ---------
__device__ __forceinline__ void mm_tile(const float* __restrict__ A,
                                        const float* __restrict__ W,
                                        float* __restrict__ C) {
  __shared__ float As[16][68];
  __shared__ float Bs[16][68];
  const int tid = threadIdx.x;
  const int tx = tid & 15;
  const int ty = tid >> 4;
  const int bm = blockIdx.x * 64;
  const int bn = blockIdx.y * 64;
  float acc[4][4] = {};
  for (int k0 = 0; k0 < 256; k0 += 16) {
    {
      const int m = tid >> 2, ks = (tid & 3) * 4;
      const float4 av = *(const float4*)(A + (bm + m) * 256 + k0 + ks);
      As[ks + 0][m] = av.x; As[ks + 1][m] = av.y;
      As[ks + 2][m] = av.z; As[ks + 3][m] = av.w;
    }
    {
      const int kk = tid >> 4, n4 = (tid & 15) * 4;
      const float4 wv = *(const float4*)(W + (k0 + kk) * 256 + bn + n4);
      Bs[kk][n4 + 0] = wv.x; Bs[kk][n4 + 1] = wv.y;
      Bs[kk][n4 + 2] = wv.z; Bs[kk][n4 + 3] = wv.w;
    }
    __syncthreads();
#pragma unroll
    for (int kk = 0; kk < 16; ++kk) {
      const float a0 = As[kk][ty * 4 + 0];
      const float a1 = As[kk][ty * 4 + 1];
      const float a2 = As[kk][ty * 4 + 2];
      const float a3 = As[kk][ty * 4 + 3];
      const float4 b = *(const float4*)(&Bs[kk][tx * 4]);
      acc[0][0] = fmaf(a0, b.x, acc[0][0]); acc[0][1] = fmaf(a0, b.y, acc[0][1]);
      acc[0][2] = fmaf(a0, b.z, acc[0][2]); acc[0][3] = fmaf(a0, b.w, acc[0][3]);
      acc[1][0] = fmaf(a1, b.x, acc[1][0]); acc[1][1] = fmaf(a1, b.y, acc[1][1]);
      acc[1][2] = fmaf(a1, b.z, acc[1][2]); acc[1][3] = fmaf(a1, b.w, acc[1][3]);
      acc[2][0] = fmaf(a2, b.x, acc[2][0]); acc[2][1] = fmaf(a2, b.y, acc[2][1]);
      acc[2][2] = fmaf(a2, b.z, acc[2][2]); acc[2][3] = fmaf(a2, b.w, acc[2][3]);
      acc[3][0] = fmaf(a3, b.x, acc[3][0]); acc[3][1] = fmaf(a3, b.y, acc[3][1]);
      acc[3][2] = fmaf(a3, b.z, acc[3][2]); acc[3][3] = fmaf(a3, b.w, acc[3][3]);
    }
    __syncthreads();
  }
#pragma unroll
  for (int i = 0; i < 4; ++i) {
    float4 o;
    o.x = acc[i][0]; o.y = acc[i][1]; o.z = acc[i][2]; o.w = acc[i][3];
    *(float4*)(C + (bm + ty * 4 + i) * 256 + bn + tx * 4) = o;
  }
}

// batched power GEMM: z -> set=z/per, i=z%per; C[set,i] = A[set,i] @ B[set]
__global__ __launch_bounds__(256, 4) void k_powmm(const float* __restrict__ A,
                                                  const float* __restrict__ B,
                                                  float* __restrict__ C,
                                                  long sA, long sB, long sC, int per) {
  const int z = blockIdx.z;
  const int set = z / per, i = z % per;
  mm_tile(A + set * sA + (long)i * 65536, B + set * sB, C + set * sC + (long)i * 65536);
}

__global__ void k_copy2(const float* __restrict__ a, const float* __restrict__ b,
                        float* __restrict__ c0, float* __restrict__ c1) {
  const int i = (blockIdx.x * 256 + threadIdx.x) * 4;
  *(float4*)(c0 + i) = *(const float4*)(a + i);
  *(float4*)(c1 + i) = *(const float4*)(b + i);
}

// transpose+cast f32[256][256] -> bf16 out[n][k]; grid (16 tiles, 37 mats)
__global__ __launch_bounds__(256, 2) void k_castT(const float* __restrict__ slabF,
                                                  const float* __restrict__ Wi1,
                                                  const float* __restrict__ m0W,
                                                  const float* __restrict__ m1W,
                                                  ushort_t* __restrict__ slabT,
                                                  ushort_t* __restrict__ WtT) {
  const int mat = blockIdx.y;
  const float* src;
  ushort_t* dst;
  if (mat < 32)      { src = slabF + (long)mat * 65536;        dst = slabT + (long)mat * 65536; }
  else if (mat == 32){ src = Wi1;                              dst = WtT; }
  else if (mat < 35) { src = m0W + (long)(mat - 33) * 65536;   dst = WtT + (long)(mat - 32) * 65536; }
  else               { src = m1W + (long)(mat - 35) * 65536;   dst = WtT + (long)(mat - 32) * 65536; }  // FIX: was mat-33
  const int rt = blockIdx.x >> 2, ct = blockIdx.x & 3;
  __shared__ float T[64][65];
  const int tid = threadIdx.x;
  {
    const int r = tid >> 2, cs = (tid & 3) * 16;
#pragma unroll
    for (int i = 0; i < 4; ++i) {
      const float4 v = *(const float4*)(src + (rt * 64 + r) * 256 + ct * 64 + cs + i * 4);
      T[r][cs + i * 4 + 0] = v.x; T[r][cs + i * 4 + 1] = v.y;
      T[r][cs + i * 4 + 2] = v.z; T[r][cs + i * 4 + 3] = v.w;
    }
  }
  __syncthreads();
  const int on = tid >> 2, ks = (tid & 3) * 16;
  ushort8 p0, p1;
#pragma unroll
  for (int i = 0; i < 8; ++i) p0[i] = bfc(T[ks + i][on]);
#pragma unroll
  for (int i = 0; i < 8; ++i) p1[i] = bfc(T[ks + 8 + i][on]);
  ushort_t* d = dst + (ct * 64 + on) * 256 + rt * 64 + ks;
  *(ushort8*)d = p0;
  *(ushort8*)(d + 8) = p1;
}

// ---------------- embedding ----------------
__global__ void k_embed(const int* __restrict__ x, const float* __restrict__ Wi,
                        const float* __restrict__ bi, float* __restrict__ u) {
  const int n = blockIdx.x;
  const int d = threadIdx.x;
  const int t = x[n];
  u[(long)n * DD + d] = Wi[t * DD + d] + bi[d];
}

// ---------------- f32 sequential chunk scan (pass1 / small levels) -----------
__global__ __launch_bounds__(512, 2) void k_scan(const float* __restrict__ u,
                                                 const float* __restrict__ W,
                                                 const float* __restrict__ Einit,
                                                 float* __restrict__ out_full,
                                                 float* __restrict__ out_ends,
                                                 int steps, int cper) {
  const int d = threadIdx.x & 255;
  const int half = threadIdx.x >> 8;
  const long r0 = (long)blockIdx.x * 2;
  __shared__ __align__(16) float hbuf[2][DD];
  __shared__ __align__(16) float psum[2][DD];

  float w[128];
  {
    const float* Wc = W + (long)(half * 128) * DD + d;
#pragma unroll
    for (int i = 0; i < 128; ++i) w[i] = Wc[(long)i * DD];
  }

  if (half == 0) {
#pragma unroll
    for (int g = 0; g < 2; ++g) {
      const long r = r0 + g;
      float hv = 0.f;
      if (Einit != nullptr && (int)(r % cper) != 0) hv = Einit[(r - 1) * DD + d];
      hbuf[g][d] = hv;
    }
  }
  __syncthreads();

  const float* __restrict__ ur0 = u + r0 * steps * DD + d;
  const float* __restrict__ ur1 = ur0 + (long)steps * DD;
  float* of0 = out_full ? out_full + r0 * steps * DD + d : nullptr;
  float* of1 = of0 ? of0 + (long)steps * DD : nullptr;
  const int e0 = half * 128;

  for (int t = 0; t < steps; ++t) {
    float uv0 = 0.f, uv1 = 0.f;
    if (half == 0) { uv0 = ur0[(long)t * DD]; uv1 = ur1[(long)t * DD]; }
    float a00 = 0.f, a01 = 0.f, a10 = 0.f, a11 = 0.f;
    const float4* hb0 = (const float4*)(&hbuf[0][e0]);
    const float4* hb1 = (const float4*)(&hbuf[1][e0]);
#pragma unroll
    for (int i = 0; i < 32; ++i) {
      const float4 h0 = hb0[i];
      const float4 h1 = hb1[i];
      a00 = fmaf(h0.x, w[4 * i + 0], a00);
      a01 = fmaf(h0.y, w[4 * i + 1], a01);
      a00 = fmaf(h0.z, w[4 * i + 2], a00);
      a01 = fmaf(h0.w, w[4 * i + 3], a01);
      a10 = fmaf(h1.x, w[4 * i + 0], a10);
      a11 = fmaf(h1.y, w[4 * i + 1], a11);
      a10 = fmaf(h1.z, w[4 * i + 2], a10);
      a11 = fmaf(h1.w, w[4 * i + 3], a11);
    }
    const float p0 = a00 + a01;
    const float p1 = a10 + a11;
    __syncthreads();
    if (half == 1) { psum[0][d] = p0; psum[1][d] = p1; }
    __syncthreads();
    if (half == 0) {
      const float n0 = p0 + psum[0][d] + uv0;
      const float n1 = p1 + psum[1][d] + uv1;
      hbuf[0][d] = n0; hbuf[1][d] = n1;
      if (of0) { of0[(long)t * DD] = n0; of1[(long)t * DD] = n1; }
    }
    __syncthreads();
  }
  if (out_ends != nullptr && half == 0) {
    out_ends[r0 * DD + d] = hbuf[0][d];
    out_ends[(r0 + 1) * DD + d] = hbuf[1][d];
  }
}

// ---------------- bf16 MFMA GEMM: C[M][256] = A[M][256] @ W + bias -----------
// BT is bf16 pre-transposed [n][k]. STATS: fuse per-column sum/sumsq atomics.
template <int STATS>
__global__ __launch_bounds__(256, 2) void k_gemm(const float* __restrict__ A,
                                                 const ushort_t* __restrict__ BT,
                                                 const float* __restrict__ bias,
                                                 float* __restrict__ C,
                                                 float* __restrict__ stats) {
  __shared__ __align__(16) ushort_t As[128 * 64];
  __shared__ __align__(16) ushort_t Bs[128 * 64];
  const int tid = threadIdx.x;
  const int lane = tid & 63;
  const int wave = tid >> 6;
  const int wr = wave >> 1, wc = wave & 1;
  const long m0 = (long)blockIdx.x * 128;
  const int n0 = blockIdx.y * 128;
  f32x4 acc[4][4];
#pragma unroll
  for (int i = 0; i < 4; ++i)
#pragma unroll
    for (int jn = 0; jn < 4; ++jn) acc[i][jn] = {0.f, 0.f, 0.f, 0.f};

  const int sr = tid >> 3;
  const int sk = (tid & 7) * 8;
#pragma unroll 1
  for (int kt = 0; kt < 4; ++kt) {
    const int kg = kt * 64;
#pragma unroll
    for (int it = 0; it < 4; ++it) {
      const int r = sr + it * 32;
      const float* src = A + (m0 + r) * 256 + kg + sk;
      const float4 f0 = *(const float4*)src;
      const float4 f1 = *(const float4*)(src + 4);
      ushort8 p;
      p[0] = bfc(f0.x); p[1] = bfc(f0.y); p[2] = bfc(f0.z); p[3] = bfc(f0.w);
      p[4] = bfc(f1.x); p[5] = bfc(f1.y); p[6] = bfc(f1.z); p[7] = bfc(f1.w);
      *(ushort8*)&As[(r * 64 + sk) ^ ((r & 7) << 3)] = p;
    }
#pragma unroll
    for (int it = 0; it < 4; ++it) {
      const int n = sr + it * 32;
      const ushort8 p = *(const ushort8*)(BT + (long)(n0 + n) * 256 + kg + sk);
      *(ushort8*)&Bs[(n * 64 + sk) ^ ((n & 7) << 3)] = p;
    }
    __syncthreads();
#pragma unroll
    for (int kk = 0; kk < 2; ++kk) {
      const int kb = kk * 32 + (lane >> 4) * 8;
      bf16x8 af[4], bfr[4];
#pragma unroll
      for (int m = 0; m < 4; ++m) {
        const int row = wr * 64 + m * 16 + (lane & 15);
        af[m] = ldsbf(As, (row * 64 + kb) ^ ((row & 7) << 3));
      }
#pragma unroll
      for (int n = 0; n < 4; ++n) {
        const int col = wc * 64 + n * 16 + (lane & 15);
        bfr[n] = ldsbf(Bs, (col * 64 + kb) ^ ((col & 7) << 3));
      }
#pragma unroll
      for (int m = 0; m < 4; ++m)
#pragma unroll
        for (int n = 0; n < 4; ++n)
          acc[m][n] = mfma16(af[m], bfr[n], acc[m][n]);
    }
    __syncthreads();
  }
  const int crow = (lane >> 4) * 4;
  const int ccol = lane & 15;
#pragma unroll
  for (int n = 0; n < 4; ++n) {
    const int col = n0 + wc * 64 + n * 16 + ccol;
    const float bv = bias[col];
    float cs = 0.f, cq = 0.f;
#pragma unroll
    for (int m = 0; m < 4; ++m) {
      const long rbase = m0 + wr * 64 + m * 16 + crow;
#pragma unroll
      for (int i = 0; i < 4; ++i) {
        const float v = acc[m][n][i] + bv;
        C[(rbase + i) * 256 + col] = v;
        if (STATS) { cs += v; cq = fmaf(v, v, cq); }
      }
    }
    if (STATS) {
      cs += __shfl_xor(cs, 16); cq += __shfl_xor(cq, 16);
      cs += __shfl_xor(cs, 32); cq += __shfl_xor(cq, 32);
      if ((lane >> 4) == 0) {
        atomicAdd(&stats[col], cs);
        atomicAdd(&stats[256 + col], cq);
      }
    }
  }
}

// ---------------- correction: H[c*16+j] += Init[c] @ Wh^{j+1} ----------------
// grid (8, 2, 16): 128-chunk tile, 128-col tile, j. Init[c]=EE1[c-1] (0 at seq start)
__global__ __launch_bounds__(256, 2) void k_corr(const float* __restrict__ EE1,
                                                 const ushort_t* __restrict__ slabT,
                                                 float* __restrict__ H) {
  __shared__ __align__(16) ushort_t As[128 * 64];
  __shared__ __align__(16) ushort_t Bs[128 * 64];
  const int tid = threadIdx.x;
  const int lane = tid & 63;
  const int wave = tid >> 6;
  const int wr = wave >> 1, wc = wave & 1;
  const int m0 = blockIdx.x * 128;
  const int n0 = blockIdx.y * 128;
  const int j = blockIdx.z;
  const ushort_t* BT = slabT + (long)j * 65536;
  f32x4 acc[4][4];
#pragma unroll
  for (int i = 0; i < 4; ++i)
#pragma unroll
    for (int jn = 0; jn < 4; ++jn) acc[i][jn] = {0.f, 0.f, 0.f, 0.f};

  const int sr = tid >> 3;
  const int sk = (tid & 7) * 8;
#pragma unroll 1
  for (int kt = 0; kt < 4; ++kt) {
    const int kg = kt * 64;
#pragma unroll
    for (int it = 0; it < 4; ++it) {
      const int c = m0 + sr + it * 32;
      ushort8 p;
#pragma unroll
      for (int q = 0; q < 8; ++q) p[q] = 0;
      if ((c & 127) != 0) {
        const float* src = EE1 + (long)(c - 1) * 256 + kg + sk;
        const float4 f0 = *(const float4*)src;
        const float4 f1 = *(const float4*)(src + 4);
        p[0] = bfc(f0.x); p[1] = bfc(f0.y); p[2] = bfc(f0.z); p[3] = bfc(f0.w);
        p[4] = bfc(f1.x); p[5] = bfc(f1.y); p[6] = bfc(f1.z); p[7] = bfc(f1.w);
      }
      const int r = sr + it * 32;
      *(ushort8*)&As[(r * 64 + sk) ^ ((r & 7) << 3)] = p;
    }
#pragma unroll
    for (int it = 0; it < 4; ++it) {
      const int n = sr + it * 32;
      const ushort8 p = *(const ushort8*)(BT + (long)(n0 + n) * 256 + kg + sk);
      *(ushort8*)&Bs[(n * 64 + sk) ^ ((n & 7) << 3)] = p;
    }
    __syncthreads();
#pragma unroll
    for (int kk = 0; kk < 2; ++kk) {
      const int kb = kk * 32 + (lane >> 4) * 8;
      bf16x8 af[4], bfr[4];
#pragma unroll
      for (int m = 0; m < 4; ++m) {
        const int row = wr * 64 + m * 16 + (lane & 15);
        af[m] = ldsbf(As, (row * 64 + kb) ^ ((row & 7) << 3));
      }
#pragma unroll
      for (int n = 0; n < 4; ++n) {
        const int col = wc * 64 + n * 16 + (lane & 15);
        bfr[n] = ldsbf(Bs, (col * 64 + kb) ^ ((col & 7) << 3));
      }
#pragma unroll
      for (int m = 0; m < 4; ++m)
#pragma unroll
        for (int n = 0; n < 4; ++n)
          acc[m][n] = mfma16(af[m], bfr[n], acc[m][n]);
    }
    __syncthreads();
  }
  const int crow = (lane >> 4) * 4;
  const int ccol = lane & 15;
#pragma unroll
  for (int m = 0; m < 4; ++m) {
    const int cbase = m0 + wr * 64 + m * 16 + crow;
#pragma unroll
    for (int n = 0; n < 4; ++n) {
      const int col = n0 + wc * 64 + n * 16 + ccol;
#pragma unroll
      for (int i = 0; i < 4; ++i) {
        float* p = H + ((long)(cbase + i) * 16 + j) * 256 + col;
        *p += acc[m][n][i];
      }
    }
  }
}

// ---------------- fused bn + gelu + residual ---------------------------------
__global__ __launch_bounds__(256) void k_bngelu(const float* __restrict__ y,
                                                const float* __restrict__ stats,
                                                const float* __restrict__ scale,
                                                const float* __restrict__ bias,
                                                float* __restrict__ x) {
  const long i4 = ((long)blockIdx.x * 256 + threadIdx.x) * 4;
  const int d = (int)(i4 & 255);
  const float4 yv = *(const float4*)(y + i4);
  const float4 xv = *(const float4*)(x + i4);
  const float4 sm = *(const float4*)(stats + d);
  const float4 sq = *(const float4*)(stats + DD + d);
  const float4 sc = *(const float4*)(scale + d);
  const float4 bi = *(const float4*)(bias + d);
  float4 o;
  {
    const float mu = sm.x * (1.f / NTOT);
    const float a = sc.x * rsqrtf(sq.x * (1.f / NTOT) - mu * mu + EPSV);
    o.x = gelu_fast((yv.x - mu) * a + bi.x) + xv.x;
  }
  {
    const float mu = sm.y * (1.f / NTOT);
    const float a = sc.y * rsqrtf(sq.y * (1.f / NTOT) - mu * mu + EPSV);
    o.y = gelu_fast((yv.y - mu) * a + bi.y) + xv.y;
  }
  {
    const float mu = sm.z * (1.f / NTOT);
    const float a = sc.z * rsqrtf(sq.z * (1.f / NTOT) - mu * mu + EPSV);
    o.z = gelu_fast((yv.z - mu) * a + bi.z) + xv.z;
  }
  {
    const float mu = sm.w * (1.f / NTOT);
    const float a = sc.w * rsqrtf(sq.w * (1.f / NTOT) - mu * mu + EPSV);
    o.w = gelu_fast((yv.w - mu) * a + bi.w) + xv.w;
  }
  *(float4*)(x + i4) = o;
}

// ---------------- logits via MFMA (N=6 padded to 16) -------------------------
__global__ __launch_bounds__(256, 2) void k_logits(const float* __restrict__ h,
                                                   const float* __restrict__ Wr,
                                                   const float* __restrict__ br,
                                                   float* __restrict__ out) {
  __shared__ __align__(16) ushort_t Hs[64 * 256];
  __shared__ __align__(16) ushort_t Ws[16 * 256];
  const int tid = threadIdx.x, lane = tid & 63, wave = tid >> 6;
  const long r0 = (long)blockIdx.x * 64;
  const int hr = tid >> 2;
#pragma unroll
  for (int it = 0; it < 8; ++it) {
    const int kq = (tid & 3) * 8 + it * 32;
    const float* src = h + (r0 + hr) * 256 + kq;
    const float4 f0 = *(const float4*)src;
    const float4 f1 = *(const float4*)(src + 4);
    ushort8 p;
    p[0] = bfc(f0.x); p[1] = bfc(f0.y); p[2] = bfc(f0.z); p[3] = bfc(f0.w);
    p[4] = bfc(f1.x); p[5] = bfc(f1.y); p[6] = bfc(f1.z); p[7] = bfc(f1.w);
    *(ushort8*)&Hs[(hr * 256 + kq) ^ ((hr & 7) << 3)] = p;
  }
  {
    float w6[6];
#pragma unroll
    for (int v = 0; v < 6; ++v) w6[v] = Wr[tid * 6 + v];
#pragma unroll
    for (int v = 0; v < 16; ++v)
      Ws[(v * 256 + tid) ^ ((v & 7) << 3)] = (v < 6) ? bfc(w6[v]) : (ushort_t)0;
  }
  __syncthreads();
  f32x4 acc = {0.f, 0.f, 0.f, 0.f};
  const int arow = wave * 16 + (lane & 15);
  const int vcol = lane & 15;
#pragma unroll
  for (int kk = 0; kk < 8; ++kk) {
    const int kb = kk * 32 + (lane >> 4) * 8;
    const bf16x8 a = ldsbf(Hs, (arow * 256 + kb) ^ ((arow & 7) << 3));
    const bf16x8 b = ldsbf(Ws, (vcol * 256 + kb) ^ ((vcol & 7) << 3));
    acc = mfma16(a, b, acc);
  }
  if (vcol < 6) {
    const float bv = br[vcol];
    const long rb = r0 + wave * 16 + (lane >> 4) * 4;
#pragma unroll
    for (int i = 0; i < 4; ++i) out[(rb + i) * 6 + vcol] = acc[i] + bv;
  }
}

extern "C" void kernel_launch(void* const* d_in, const int* in_sizes, int n_in,
                              void* d_out, int out_size, void* d_ws, size_t ws_size,
                              hipStream_t stream) {
  const int* x = (const int*)d_in[0];
  const float* Wi0 = (const float*)d_in[1];
  const float* bi0 = (const float*)d_in[2];
  const float* Wh0 = (const float*)d_in[3];
  const float* m0W = (const float*)d_in[4];
  const float* m0b = (const float*)d_in[5];
  const float* m0s = (const float*)d_in[6];
  const float* m0bi = (const float*)d_in[7];
  const float* Wi1 = (const float*)d_in[8];
  const float* bi1 = (const float*)d_in[9];
  const float* Wh1 = (const float*)d_in[10];
  const float* m1W = (const float*)d_in[11];
  const float* m1b = (const float*)d_in[12];
  const float* m1s = (const float*)d_in[13];
  const float* m1bi = (const float*)d_in[14];
  const float* Wr = (const float*)d_in[15];
  const float* br = (const float*)d_in[16];

  float* ws = (float*)d_ws;
  float* u = ws + OFF_U;
  float* h = ws + OFF_H;
  float* e1 = ws + OFF_E1;
  float* ee1 = ws + OFF_EE1;
  float* e2 = ws + OFF_E2;
  float* t2 = ws + OFF_T2;
  float* stats = ws + OFF_ST;
  float* slabF = ws + OFF_SLABF;
  float* P256F = ws + OFF_P256F;
  float* tA = ws + OFF_TA;
  float* tB = ws + OFF_TB;
  ushort_t* slabT = (ushort_t*)(ws + OFF_SLABT);
  ushort_t* WtT = (ushort_t*)(ws + OFF_WTT);
  const long SS = 16L * 65536;  // set stride (elements)

  // power slab: slab[i] = Wh^{i+1}, i=0..15, both param sets; P256 = Wh^256
  k_copy2<<<64, 256, 0, stream>>>(Wh0, Wh1, slabF, slabF + SS);
  k_powmm<<<dim3(4, 4, 2), 256, 0, stream>>>(slabF, slabF, slabF + 65536, SS, SS, SS, 1);
  k_powmm<<<dim3(4, 4, 4), 256, 0, stream>>>(slabF, slabF + 65536, slabF + 2 * 65536, SS, SS, SS, 2);
  k_powmm<<<dim3(4, 4, 8), 256, 0, stream>>>(slabF, slabF + 3 * 65536, slabF + 4 * 65536, SS, SS, SS, 4);
  k_powmm<<<dim3(4, 4, 16), 256, 0, stream>>>(slabF, slabF + 7 * 65536, slabF + 8 * 65536, SS, SS, SS, 8);
  k_powmm<<<dim3(4, 4, 2), 256, 0, stream>>>(slabF + 15 * 65536, slabF + 15 * 65536, tA, SS, SS, 65536, 1); // ^32
  k_powmm<<<dim3(4, 4, 2), 256, 0, stream>>>(tA, tA, tB, 65536, 65536, 65536, 1);   // ^64
  k_powmm<<<dim3(4, 4, 2), 256, 0, stream>>>(tB, tB, tA, 65536, 65536, 65536, 1);   // ^128
  k_powmm<<<dim3(4, 4, 2), 256, 0, stream>>>(tA, tA, P256F, 65536, 65536, 65536, 1);// ^256
  k_castT<<<dim3(16, 37), 256, 0, stream>>>(slabF, Wi1, m0W, m1W, slabT, WtT);
  hipMemsetAsync(stats, 0, 8 * 512 * sizeof(float), stream);

  for (int blk = 0; blk < 4; ++blk) {
    const int pi = blk ? 1 : 0;
    const float* Wh = pi ? Wh1 : Wh0;
    const float* P16f = slabF + pi * SS + 15 * 65536;
    const float* P256f = P256F + pi * 65536;
    const ushort_t* slabTp = slabT + pi * SS;
    const float* mb = pi ? m1b : m0b;
    const float* msc = pi ? m1s : m0s;
    const float* mbi = pi ? m1bi : m0bi;

    if (blk == 0) {
      k_embed<<<NTOT, 256, 0, stream>>>(x, Wi0, bi0, u);
    } else {
      k_gemm<0><<<dim3(128, 2), 256, 0, stream>>>(h, WtT, bi1, u, nullptr);
    }

    // pass1 local scan (full outputs) + hierarchical true-init computation
    k_scan<<<512, 512, 0, stream>>>(u, Wh, nullptr, h, e1, L1C, 1);
    k_scan<<<32, 512, 0, stream>>>(e1, P16f, nullptr, nullptr, e2, 16, 1);
    k_scan<<<4, 512, 0, stream>>>(e2, P256f, nullptr, t2, nullptr, 8, 1);
    k_scan<<<32, 512, 0, stream>>>(e1, P16f, t2, ee1, nullptr, 16, 8);
    // h += Init @ Wh^{j+1}  (batched over j)
    k_corr<<<dim3(8, 2, 16), 256, 0, stream>>>(ee1, slabTp, h);

    for (int l = 0; l < 2; ++l) {
      float* statsL = stats + (blk * 2 + l) * 512;
      const ushort_t* Wt = WtT + (1 + pi * 2 + l) * 65536;
      k_gemm<1><<<dim3(128, 2), 256, 0, stream>>>(h, Wt, mb + l * 256, u, statsL);
      k_bngelu<<<NTOT * DD / 1024, 256, 0, stream>>>(u, statsL, msc + l * 256,
                                                     mbi + l * 256, h);
    }
  }

  k_logits<<<256, 256, 0, stream>>>(h, Wr, br, (float*)d_out);
}

// Round 6
// 869.953 us; speedup vs baseline: 1.4403x; 1.0942x over previous
//
#include <hip/hip_runtime.h>
#include <hip/hip_bf16.h>

// LRUModel r6: pass-1 scan moved to MFMA (fp16, W in registers, fp16 LDS state),
// all GEMM dtypes bf16 -> fp16 (8x mantissa headroom, same speed).
// B=8,S=2048,D=256,V=6, 4 blocks of [linear-RNN scan -> 2x(Linear+BN+gelu+res)]
//  - pass1: k_scan_mfma, 64 blocks x 16 chunks x 16 steps, h_local + E1 ends
//  - lvl2/lvl3 small f32 VALU scans -> true chunk inits EE1 (exact)
//  - correction: h += init_c @ Wh^{j+1}, batched fp16 MFMA GEMM over j
//  - MLP/u-drive GEMMs: fp16 MFMA, col-stats fused in epilogue
//  - logits: MFMA with N padded 6->16

#define DD 256
#define NTOT 16384
#define L1C 16
#define EPSV 1e-5f

typedef unsigned short ushort_t;
typedef __attribute__((ext_vector_type(8))) unsigned short ushort8;
typedef __attribute__((ext_vector_type(8))) _Float16 f16x8;
typedef __attribute__((ext_vector_type(4))) float f32x4;

// ws layout (float offsets)
#define OFF_U     0L
#define OFF_H     4194304L
#define OFF_E1    8388608L    // 1024*256
#define OFF_EE1   8650752L    // 1024*256
#define OFF_E2    8912896L    // 64*256
#define OFF_T2    8929280L    // 64*256
#define OFF_ST    8945664L    // 8*512 stats slabs
#define OFF_SLABF 8949760L    // 2*16*65536 f32 power slab Wh^1..Wh^16
#define OFF_P256F 11046912L   // 2*65536
#define OFF_TA    11177984L   // 2*65536
#define OFF_TB    11309056L   // 2*65536
#define OFF_SLABT 11440128L   // 2*16*65536 ushort (fp16 transposed slab)
#define OFF_WTT   12488704L   // 5*65536 ushort (Wi1,m0W0,m0W1,m1W0,m1W1 fp16 T)

__device__ __forceinline__ ushort_t hc(float f) {
  return __builtin_bit_cast(ushort_t, (_Float16)f);  // v_cvt_f16_f32 RNE
}

__device__ __forceinline__ f16x8 ldsf16(const ushort_t* p, int idx) {
  return __builtin_bit_cast(f16x8, *(const ushort8*)(p + idx));
}

__device__ __forceinline__ f32x4 mfma16h(f16x8 a, f16x8 b, f32x4 c) {
  return __builtin_amdgcn_mfma_f32_16x16x32_f16(a, b, c, 0, 0, 0);
}

__device__ __forceinline__ float gelu_fast(float x) {
  const float z = 0.7978845608028654f * (x + 0.044715f * x * x * x);
  return x / (1.f + __expf(-2.f * z));  // x * sigmoid(2z) == 0.5x(1+tanh z)
}

// ---------------- f32 64x64-tile GEMM (power-slab construction only) ---------
__device__ __forceinline__ void mm_tile(const float* __restrict__ A,
                                        const float* __restrict__ W,
                                        float* __restrict__ C) {
  __shared__ float As[16][68];
  __shared__ float Bs[16][68];
  const int tid = threadIdx.x;
  const int tx = tid & 15;
  const int ty = tid >> 4;
  const int bm = blockIdx.x * 64;
  const int bn = blockIdx.y * 64;
  float acc[4][4] = {};
  for (int k0 = 0; k0 < 256; k0 += 16) {
    {
      const int m = tid >> 2, ks = (tid & 3) * 4;
      const float4 av = *(const float4*)(A + (bm + m) * 256 + k0 + ks);
      As[ks + 0][m] = av.x; As[ks + 1][m] = av.y;
      As[ks + 2][m] = av.z; As[ks + 3][m] = av.w;
    }
    {
      const int kk = tid >> 4, n4 = (tid & 15) * 4;
      const float4 wv = *(const float4*)(W + (k0 + kk) * 256 + bn + n4);
      Bs[kk][n4 + 0] = wv.x; Bs[kk][n4 + 1] = wv.y;
      Bs[kk][n4 + 2] = wv.z; Bs[kk][n4 + 3] = wv.w;
    }
    __syncthreads();
#pragma unroll
    for (int kk = 0; kk < 16; ++kk) {
      const float a0 = As[kk][ty * 4 + 0];
      const float a1 = As[kk][ty * 4 + 1];
      const float a2 = As[kk][ty * 4 + 2];
      const float a3 = As[kk][ty * 4 + 3];
      const float4 b = *(const float4*)(&Bs[kk][tx * 4]);
      acc[0][0] = fmaf(a0, b.x, acc[0][0]); acc[0][1] = fmaf(a0, b.y, acc[0][1]);
      acc[0][2] = fmaf(a0, b.z, acc[0][2]); acc[0][3] = fmaf(a0, b.w, acc[0][3]);
      acc[1][0] = fmaf(a1, b.x, acc[1][0]); acc[1][1] = fmaf(a1, b.y, acc[1][1]);
      acc[1][2] = fmaf(a1, b.z, acc[1][2]); acc[1][3] = fmaf(a1, b.w, acc[1][3]);
      acc[2][0] = fmaf(a2, b.x, acc[2][0]); acc[2][1] = fmaf(a2, b.y, acc[2][1]);
      acc[2][2] = fmaf(a2, b.z, acc[2][2]); acc[2][3] = fmaf(a2, b.w, acc[2][3]);
      acc[3][0] = fmaf(a3, b.x, acc[3][0]); acc[3][1] = fmaf(a3, b.y, acc[3][1]);
      acc[3][2] = fmaf(a3, b.z, acc[3][2]); acc[3][3] = fmaf(a3, b.w, acc[3][3]);
    }
    __syncthreads();
  }
#pragma unroll
  for (int i = 0; i < 4; ++i) {
    float4 o;
    o.x = acc[i][0]; o.y = acc[i][1]; o.z = acc[i][2]; o.w = acc[i][3];
    *(float4*)(C + (bm + ty * 4 + i) * 256 + bn + tx * 4) = o;
  }
}

// batched power GEMM: z -> set=z/per, i=z%per; C[set,i] = A[set,i] @ B[set]
__global__ __launch_bounds__(256, 4) void k_powmm(const float* __restrict__ A,
                                                  const float* __restrict__ B,
                                                  float* __restrict__ C,
                                                  long sA, long sB, long sC, int per) {
  const int z = blockIdx.z;
  const int set = z / per, i = z % per;
  mm_tile(A + set * sA + (long)i * 65536, B + set * sB, C + set * sC + (long)i * 65536);
}

__global__ void k_copy2(const float* __restrict__ a, const float* __restrict__ b,
                        float* __restrict__ c0, float* __restrict__ c1) {
  const int i = (blockIdx.x * 256 + threadIdx.x) * 4;
  *(float4*)(c0 + i) = *(const float4*)(a + i);
  *(float4*)(c1 + i) = *(const float4*)(b + i);
}

// transpose+cast f32[256][256] -> fp16 out[n][k]; grid (16 tiles, 37 mats)
__global__ __launch_bounds__(256, 2) void k_castT(const float* __restrict__ slabF,
                                                  const float* __restrict__ Wi1,
                                                  const float* __restrict__ m0W,
                                                  const float* __restrict__ m1W,
                                                  ushort_t* __restrict__ slabT,
                                                  ushort_t* __restrict__ WtT) {
  const int mat = blockIdx.y;
  const float* src;
  ushort_t* dst;
  if (mat < 32)      { src = slabF + (long)mat * 65536;        dst = slabT + (long)mat * 65536; }
  else if (mat == 32){ src = Wi1;                              dst = WtT; }
  else if (mat < 35) { src = m0W + (long)(mat - 33) * 65536;   dst = WtT + (long)(mat - 32) * 65536; }
  else               { src = m1W + (long)(mat - 35) * 65536;   dst = WtT + (long)(mat - 32) * 65536; }
  const int rt = blockIdx.x >> 2, ct = blockIdx.x & 3;
  __shared__ float T[64][65];
  const int tid = threadIdx.x;
  {
    const int r = tid >> 2, cs = (tid & 3) * 16;
#pragma unroll
    for (int i = 0; i < 4; ++i) {
      const float4 v = *(const float4*)(src + (rt * 64 + r) * 256 + ct * 64 + cs + i * 4);
      T[r][cs + i * 4 + 0] = v.x; T[r][cs + i * 4 + 1] = v.y;
      T[r][cs + i * 4 + 2] = v.z; T[r][cs + i * 4 + 3] = v.w;
    }
  }
  __syncthreads();
  const int on = tid >> 2, ks = (tid & 3) * 16;
  ushort8 p0, p1;
#pragma unroll
  for (int i = 0; i < 8; ++i) p0[i] = hc(T[ks + i][on]);
#pragma unroll
  for (int i = 0; i < 8; ++i) p1[i] = hc(T[ks + 8 + i][on]);
  ushort_t* d = dst + (ct * 64 + on) * 256 + rt * 64 + ks;
  *(ushort8*)d = p0;
  *(ushort8*)(d + 8) = p1;
}

// ---------------- embedding ----------------
__global__ void k_embed(const int* __restrict__ x, const float* __restrict__ Wi,
                        const float* __restrict__ bi, float* __restrict__ u) {
  const int n = blockIdx.x;
  const int d = threadIdx.x;
  const int t = x[n];
  u[(long)n * DD + d] = Wi[t * DD + d] + bi[d];
}

// ---------------- MFMA pass-1 scan ------------------------------------------
// 64 blocks x 256 thr (4 waves). Block owns 16 chunks x L1C=16 steps.
// Wt: fp16 W^T [d_out][e] (slabT j=0), preloaded to 128 B-frag VGPRs/wave.
// State h: fp16 LDS [16][256], double-buffered, XOR-swizzled. 1 barrier/step.
// Outputs: H (local scan, f32) all steps; E1 chunk ends.
__global__ __launch_bounds__(256, 1) void k_scan_mfma(const float* __restrict__ u,
                                                      const ushort_t* __restrict__ Wt,
                                                      float* __restrict__ H,
                                                      float* __restrict__ E1) {
  __shared__ __align__(16) ushort_t hs[2][16 * 256];
  const int tid = threadIdx.x, lane = tid & 63, wave = tid >> 6;
  const int c0 = blockIdx.x * 16;
  const int arow = lane & 15;   // A-row / B-col / C-col lane index
  const int kgrp = lane >> 4;   // 0..3

  // preload B-fragments: wave covers cols [wave*64, wave*64+64)
  f16x8 bfrag[4][8];
#pragma unroll
  for (int nt = 0; nt < 4; ++nt) {
    const int col = wave * 64 + nt * 16 + arow;
#pragma unroll
    for (int kt = 0; kt < 8; ++kt) {
      const ushort8 p = *(const ushort8*)(Wt + col * 256 + kt * 32 + kgrp * 8);
      bfrag[nt][kt] = __builtin_bit_cast(f16x8, p);
    }
  }
  // zero state buf 0
  {
    ushort8 z;
#pragma unroll
    for (int q = 0; q < 8; ++q) z[q] = 0;
    *(ushort8*)&hs[0][tid * 8] = z;
    *(ushort8*)&hs[0][2048 + tid * 8] = z;
  }
  __syncthreads();

  int p = 0;
  for (int t = 0; t < L1C; ++t) {
    f16x8 afrag[8];
#pragma unroll
    for (int kt = 0; kt < 8; ++kt) {
      const int idx = arow * 256 + kt * 32 + kgrp * 8;
      afrag[kt] = ldsf16(hs[p], idx ^ ((arow & 7) << 3));
    }
#pragma unroll
    for (int nt = 0; nt < 4; ++nt) {
      f32x4 acc = {0.f, 0.f, 0.f, 0.f};
#pragma unroll
      for (int kt = 0; kt < 8; ++kt) acc = mfma16h(afrag[kt], bfrag[nt][kt], acc);
      const int col = wave * 64 + nt * 16 + arow;
#pragma unroll
      for (int i = 0; i < 4; ++i) {
        const int m = kgrp * 4 + i;  // chunk within block
        const long grow = (long)(c0 + m) * L1C + t;
        const float v = acc[i] + u[grow * 256 + col];
        H[grow * 256 + col] = v;
        const int idx = m * 256 + col;
        hs[p ^ 1][idx ^ ((m & 7) << 3)] = hc(v);
        if (t == L1C - 1) E1[(long)(c0 + m) * 256 + col] = v;
      }
    }
    __syncthreads();
    p ^= 1;
  }
}

// ---------------- f32 sequential chunk scan (small levels only) --------------
__global__ __launch_bounds__(512, 2) void k_scan(const float* __restrict__ u,
                                                 const float* __restrict__ W,
                                                 const float* __restrict__ Einit,
                                                 float* __restrict__ out_full,
                                                 float* __restrict__ out_ends,
                                                 int steps, int cper) {
  const int d = threadIdx.x & 255;
  const int half = threadIdx.x >> 8;
  const long r0 = (long)blockIdx.x * 2;
  __shared__ __align__(16) float hbuf[2][DD];
  __shared__ __align__(16) float psum[2][DD];

  float w[128];
  {
    const float* Wc = W + (long)(half * 128) * DD + d;
#pragma unroll
    for (int i = 0; i < 128; ++i) w[i] = Wc[(long)i * DD];
  }

  if (half == 0) {
#pragma unroll
    for (int g = 0; g < 2; ++g) {
      const long r = r0 + g;
      float hv = 0.f;
      if (Einit != nullptr && (int)(r % cper) != 0) hv = Einit[(r - 1) * DD + d];
      hbuf[g][d] = hv;
    }
  }
  __syncthreads();

  const float* __restrict__ ur0 = u + r0 * steps * DD + d;
  const float* __restrict__ ur1 = ur0 + (long)steps * DD;
  float* of0 = out_full ? out_full + r0 * steps * DD + d : nullptr;
  float* of1 = of0 ? of0 + (long)steps * DD : nullptr;
  const int e0 = half * 128;

  for (int t = 0; t < steps; ++t) {
    float uv0 = 0.f, uv1 = 0.f;
    if (half == 0) { uv0 = ur0[(long)t * DD]; uv1 = ur1[(long)t * DD]; }
    float a00 = 0.f, a01 = 0.f, a10 = 0.f, a11 = 0.f;
    const float4* hb0 = (const float4*)(&hbuf[0][e0]);
    const float4* hb1 = (const float4*)(&hbuf[1][e0]);
#pragma unroll
    for (int i = 0; i < 32; ++i) {
      const float4 h0 = hb0[i];
      const float4 h1 = hb1[i];
      a00 = fmaf(h0.x, w[4 * i + 0], a00);
      a01 = fmaf(h0.y, w[4 * i + 1], a01);
      a00 = fmaf(h0.z, w[4 * i + 2], a00);
      a01 = fmaf(h0.w, w[4 * i + 3], a01);
      a10 = fmaf(h1.x, w[4 * i + 0], a10);
      a11 = fmaf(h1.y, w[4 * i + 1], a11);
      a10 = fmaf(h1.z, w[4 * i + 2], a10);
      a11 = fmaf(h1.w, w[4 * i + 3], a11);
    }
    const float p0 = a00 + a01;
    const float p1 = a10 + a11;
    __syncthreads();
    if (half == 1) { psum[0][d] = p0; psum[1][d] = p1; }
    __syncthreads();
    if (half == 0) {
      const float n0 = p0 + psum[0][d] + uv0;
      const float n1 = p1 + psum[1][d] + uv1;
      hbuf[0][d] = n0; hbuf[1][d] = n1;
      if (of0) { of0[(long)t * DD] = n0; of1[(long)t * DD] = n1; }
    }
    __syncthreads();
  }
  if (out_ends != nullptr && half == 0) {
    out_ends[r0 * DD + d] = hbuf[0][d];
    out_ends[(r0 + 1) * DD + d] = hbuf[1][d];
  }
}

// ---------------- fp16 MFMA GEMM: C[M][256] = A[M][256] @ W + bias -----------
template <int STATS>
__global__ __launch_bounds__(256, 2) void k_gemm(const float* __restrict__ A,
                                                 const ushort_t* __restrict__ BT,
                                                 const float* __restrict__ bias,
                                                 float* __restrict__ C,
                                                 float* __restrict__ stats) {
  __shared__ __align__(16) ushort_t As[128 * 64];
  __shared__ __align__(16) ushort_t Bs[128 * 64];
  const int tid = threadIdx.x;
  const int lane = tid & 63;
  const int wave = tid >> 6;
  const int wr = wave >> 1, wc = wave & 1;
  const long m0 = (long)blockIdx.x * 128;
  const int n0 = blockIdx.y * 128;
  f32x4 acc[4][4];
#pragma unroll
  for (int i = 0; i < 4; ++i)
#pragma unroll
    for (int jn = 0; jn < 4; ++jn) acc[i][jn] = {0.f, 0.f, 0.f, 0.f};

  const int sr = tid >> 3;
  const int sk = (tid & 7) * 8;
#pragma unroll 1
  for (int kt = 0; kt < 4; ++kt) {
    const int kg = kt * 64;
#pragma unroll
    for (int it = 0; it < 4; ++it) {
      const int r = sr + it * 32;
      const float* src = A + (m0 + r) * 256 + kg + sk;
      const float4 f0 = *(const float4*)src;
      const float4 f1 = *(const float4*)(src + 4);
      ushort8 p;
      p[0] = hc(f0.x); p[1] = hc(f0.y); p[2] = hc(f0.z); p[3] = hc(f0.w);
      p[4] = hc(f1.x); p[5] = hc(f1.y); p[6] = hc(f1.z); p[7] = hc(f1.w);
      *(ushort8*)&As[(r * 64 + sk) ^ ((r & 7) << 3)] = p;
    }
#pragma unroll
    for (int it = 0; it < 4; ++it) {
      const int n = sr + it * 32;
      const ushort8 p = *(const ushort8*)(BT + (long)(n0 + n) * 256 + kg + sk);
      *(ushort8*)&Bs[(n * 64 + sk) ^ ((n & 7) << 3)] = p;
    }
    __syncthreads();
#pragma unroll
    for (int kk = 0; kk < 2; ++kk) {
      const int kb = kk * 32 + (lane >> 4) * 8;
      f16x8 af[4], bfr[4];
#pragma unroll
      for (int m = 0; m < 4; ++m) {
        const int row = wr * 64 + m * 16 + (lane & 15);
        af[m] = ldsf16(As, (row * 64 + kb) ^ ((row & 7) << 3));
      }
#pragma unroll
      for (int n = 0; n < 4; ++n) {
        const int col = wc * 64 + n * 16 + (lane & 15);
        bfr[n] = ldsf16(Bs, (col * 64 + kb) ^ ((col & 7) << 3));
      }
#pragma unroll
      for (int m = 0; m < 4; ++m)
#pragma unroll
        for (int n = 0; n < 4; ++n)
          acc[m][n] = mfma16h(af[m], bfr[n], acc[m][n]);
    }
    __syncthreads();
  }
  const int crow = (lane >> 4) * 4;
  const int ccol = lane & 15;
#pragma unroll
  for (int n = 0; n < 4; ++n) {
    const int col = n0 + wc * 64 + n * 16 + ccol;
    const float bv = bias[col];
    float cs = 0.f, cq = 0.f;
#pragma unroll
    for (int m = 0; m < 4; ++m) {
      const long rbase = m0 + wr * 64 + m * 16 + crow;
#pragma unroll
      for (int i = 0; i < 4; ++i) {
        const float v = acc[m][n][i] + bv;
        C[(rbase + i) * 256 + col] = v;
        if (STATS) { cs += v; cq = fmaf(v, v, cq); }
      }
    }
    if (STATS) {
      cs += __shfl_xor(cs, 16); cq += __shfl_xor(cq, 16);
      cs += __shfl_xor(cs, 32); cq += __shfl_xor(cq, 32);
      if ((lane >> 4) == 0) {
        atomicAdd(&stats[col], cs);
        atomicAdd(&stats[256 + col], cq);
      }
    }
  }
}

// ---------------- correction: H[c*16+j] += Init[c] @ Wh^{j+1} ----------------
__global__ __launch_bounds__(256, 2) void k_corr(const float* __restrict__ EE1,
                                                 const ushort_t* __restrict__ slabT,
                                                 float* __restrict__ H) {
  __shared__ __align__(16) ushort_t As[128 * 64];
  __shared__ __align__(16) ushort_t Bs[128 * 64];
  const int tid = threadIdx.x;
  const int lane = tid & 63;
  const int wave = tid >> 6;
  const int wr = wave >> 1, wc = wave & 1;
  const int m0 = blockIdx.x * 128;
  const int n0 = blockIdx.y * 128;
  const int j = blockIdx.z;
  const ushort_t* BT = slabT + (long)j * 65536;
  f32x4 acc[4][4];
#pragma unroll
  for (int i = 0; i < 4; ++i)
#pragma unroll
    for (int jn = 0; jn < 4; ++jn) acc[i][jn] = {0.f, 0.f, 0.f, 0.f};

  const int sr = tid >> 3;
  const int sk = (tid & 7) * 8;
#pragma unroll 1
  for (int kt = 0; kt < 4; ++kt) {
    const int kg = kt * 64;
#pragma unroll
    for (int it = 0; it < 4; ++it) {
      const int c = m0 + sr + it * 32;
      ushort8 p;
#pragma unroll
      for (int q = 0; q < 8; ++q) p[q] = 0;
      if ((c & 127) != 0) {
        const float* src = EE1 + (long)(c - 1) * 256 + kg + sk;
        const float4 f0 = *(const float4*)src;
        const float4 f1 = *(const float4*)(src + 4);
        p[0] = hc(f0.x); p[1] = hc(f0.y); p[2] = hc(f0.z); p[3] = hc(f0.w);
        p[4] = hc(f1.x); p[5] = hc(f1.y); p[6] = hc(f1.z); p[7] = hc(f1.w);
      }
      const int r = sr + it * 32;
      *(ushort8*)&As[(r * 64 + sk) ^ ((r & 7) << 3)] = p;
    }
#pragma unroll
    for (int it = 0; it < 4; ++it) {
      const int n = sr + it * 32;
      const ushort8 p = *(const ushort8*)(BT + (long)(n0 + n) * 256 + kg + sk);
      *(ushort8*)&Bs[(n * 64 + sk) ^ ((n & 7) << 3)] = p;
    }
    __syncthreads();
#pragma unroll
    for (int kk = 0; kk < 2; ++kk) {
      const int kb = kk * 32 + (lane >> 4) * 8;
      f16x8 af[4], bfr[4];
#pragma unroll
      for (int m = 0; m < 4; ++m) {
        const int row = wr * 64 + m * 16 + (lane & 15);
        af[m] = ldsf16(As, (row * 64 + kb) ^ ((row & 7) << 3));
      }
#pragma unroll
      for (int n = 0; n < 4; ++n) {
        const int col = wc * 64 + n * 16 + (lane & 15);
        bfr[n] = ldsf16(Bs, (col * 64 + kb) ^ ((col & 7) << 3));
      }
#pragma unroll
      for (int m = 0; m < 4; ++m)
#pragma unroll
        for (int n = 0; n < 4; ++n)
          acc[m][n] = mfma16h(af[m], bfr[n], acc[m][n]);
    }
    __syncthreads();
  }
  const int crow = (lane >> 4) * 4;
  const int ccol = lane & 15;
#pragma unroll
  for (int m = 0; m < 4; ++m) {
    const int cbase = m0 + wr * 64 + m * 16 + crow;
#pragma unroll
    for (int n = 0; n < 4; ++n) {
      const int col = n0 + wc * 64 + n * 16 + ccol;
#pragma unroll
      for (int i = 0; i < 4; ++i) {
        float* p = H + ((long)(cbase + i) * 16 + j) * 256 + col;
        *p += acc[m][n][i];
      }
    }
  }
}

// ---------------- fused bn + gelu + residual ---------------------------------
__global__ __launch_bounds__(256) void k_bngelu(const float* __restrict__ y,
                                                const float* __restrict__ stats,
                                                const float* __restrict__ scale,
                                                const float* __restrict__ bias,
                                                float* __restrict__ x) {
  const long i4 = ((long)blockIdx.x * 256 + threadIdx.x) * 4;
  const int d = (int)(i4 & 255);
  const float4 yv = *(const float4*)(y + i4);
  const float4 xv = *(const float4*)(x + i4);
  const float4 sm = *(const float4*)(stats + d);
  const float4 sq = *(const float4*)(stats + DD + d);
  const float4 sc = *(const float4*)(scale + d);
  const float4 bi = *(const float4*)(bias + d);
  float4 o;
  {
    const float mu = sm.x * (1.f / NTOT);
    const float a = sc.x * rsqrtf(sq.x * (1.f / NTOT) - mu * mu + EPSV);
    o.x = gelu_fast((yv.x - mu) * a + bi.x) + xv.x;
  }
  {
    const float mu = sm.y * (1.f / NTOT);
    const float a = sc.y * rsqrtf(sq.y * (1.f / NTOT) - mu * mu + EPSV);
    o.y = gelu_fast((yv.y - mu) * a + bi.y) + xv.y;
  }
  {
    const float mu = sm.z * (1.f / NTOT);
    const float a = sc.z * rsqrtf(sq.z * (1.f / NTOT) - mu * mu + EPSV);
    o.z = gelu_fast((yv.z - mu) * a + bi.z) + xv.z;
  }
  {
    const float mu = sm.w * (1.f / NTOT);
    const float a = sc.w * rsqrtf(sq.w * (1.f / NTOT) - mu * mu + EPSV);
    o.w = gelu_fast((yv.w - mu) * a + bi.w) + xv.w;
  }
  *(float4*)(x + i4) = o;
}

// ---------------- logits via MFMA (N=6 padded to 16) -------------------------
__global__ __launch_bounds__(256, 2) void k_logits(const float* __restrict__ h,
                                                   const float* __restrict__ Wr,
                                                   const float* __restrict__ br,
                                                   float* __restrict__ out) {
  __shared__ __align__(16) ushort_t Hs[64 * 256];
  __shared__ __align__(16) ushort_t Ws[16 * 256];
  const int tid = threadIdx.x, lane = tid & 63, wave = tid >> 6;
  const long r0 = (long)blockIdx.x * 64;
  const int hr = tid >> 2;
#pragma unroll
  for (int it = 0; it < 8; ++it) {
    const int kq = (tid & 3) * 8 + it * 32;
    const float* src = h + (r0 + hr) * 256 + kq;
    const float4 f0 = *(const float4*)src;
    const float4 f1 = *(const float4*)(src + 4);
    ushort8 p;
    p[0] = hc(f0.x); p[1] = hc(f0.y); p[2] = hc(f0.z); p[3] = hc(f0.w);
    p[4] = hc(f1.x); p[5] = hc(f1.y); p[6] = hc(f1.z); p[7] = hc(f1.w);
    *(ushort8*)&Hs[(hr * 256 + kq) ^ ((hr & 7) << 3)] = p;
  }
  {
    float w6[6];
#pragma unroll
    for (int v = 0; v < 6; ++v) w6[v] = Wr[tid * 6 + v];
#pragma unroll
    for (int v = 0; v < 16; ++v)
      Ws[(v * 256 + tid) ^ ((v & 7) << 3)] = (v < 6) ? hc(w6[v]) : (ushort_t)0;
  }
  __syncthreads();
  f32x4 acc = {0.f, 0.f, 0.f, 0.f};
  const int arow = wave * 16 + (lane & 15);
  const int vcol = lane & 15;
#pragma unroll
  for (int kk = 0; kk < 8; ++kk) {
    const int kb = kk * 32 + (lane >> 4) * 8;
    const f16x8 a = ldsf16(Hs, (arow * 256 + kb) ^ ((arow & 7) << 3));
    const f16x8 b = ldsf16(Ws, (vcol * 256 + kb) ^ ((vcol & 7) << 3));
    acc = mfma16h(a, b, acc);
  }
  if (vcol < 6) {
    const float bv = br[vcol];
    const long rb = r0 + wave * 16 + (lane >> 4) * 4;
#pragma unroll
    for (int i = 0; i < 4; ++i) out[(rb + i) * 6 + vcol] = acc[i] + bv;
  }
}

extern "C" void kernel_launch(void* const* d_in, const int* in_sizes, int n_in,
                              void* d_out, int out_size, void* d_ws, size_t ws_size,
                              hipStream_t stream) {
  const int* x = (const int*)d_in[0];
  const float* Wi0 = (const float*)d_in[1];
  const float* bi0 = (const float*)d_in[2];
  const float* Wh0 = (const float*)d_in[3];
  const float* m0W = (const float*)d_in[4];
  const float* m0b = (const float*)d_in[5];
  const float* m0s = (const float*)d_in[6];
  const float* m0bi = (const float*)d_in[7];
  const float* Wi1 = (const float*)d_in[8];
  const float* bi1 = (const float*)d_in[9];
  const float* Wh1 = (const float*)d_in[10];
  const float* m1W = (const float*)d_in[11];
  const float* m1b = (const float*)d_in[12];
  const float* m1s = (const float*)d_in[13];
  const float* m1bi = (const float*)d_in[14];
  const float* Wr = (const float*)d_in[15];
  const float* br = (const float*)d_in[16];

  float* ws = (float*)d_ws;
  float* u = ws + OFF_U;
  float* h = ws + OFF_H;
  float* e1 = ws + OFF_E1;
  float* ee1 = ws + OFF_EE1;
  float* e2 = ws + OFF_E2;
  float* t2 = ws + OFF_T2;
  float* stats = ws + OFF_ST;
  float* slabF = ws + OFF_SLABF;
  float* P256F = ws + OFF_P256F;
  float* tA = ws + OFF_TA;
  float* tB = ws + OFF_TB;
  ushort_t* slabT = (ushort_t*)(ws + OFF_SLABT);
  ushort_t* WtT = (ushort_t*)(ws + OFF_WTT);
  const long SS = 16L * 65536;  // set stride (elements)

  // power slab: slab[i] = Wh^{i+1}, i=0..15, both param sets; P256 = Wh^256
  k_copy2<<<64, 256, 0, stream>>>(Wh0, Wh1, slabF, slabF + SS);
  k_powmm<<<dim3(4, 4, 2), 256, 0, stream>>>(slabF, slabF, slabF + 65536, SS, SS, SS, 1);
  k_powmm<<<dim3(4, 4, 4), 256, 0, stream>>>(slabF, slabF + 65536, slabF + 2 * 65536, SS, SS, SS, 2);
  k_powmm<<<dim3(4, 4, 8), 256, 0, stream>>>(slabF, slabF + 3 * 65536, slabF + 4 * 65536, SS, SS, SS, 4);
  k_powmm<<<dim3(4, 4, 16), 256, 0, stream>>>(slabF, slabF + 7 * 65536, slabF + 8 * 65536, SS, SS, SS, 8);
  k_powmm<<<dim3(4, 4, 2), 256, 0, stream>>>(slabF + 15 * 65536, slabF + 15 * 65536, tA, SS, SS, 65536, 1); // ^32
  k_powmm<<<dim3(4, 4, 2), 256, 0, stream>>>(tA, tA, tB, 65536, 65536, 65536, 1);   // ^64
  k_powmm<<<dim3(4, 4, 2), 256, 0, stream>>>(tB, tB, tA, 65536, 65536, 65536, 1);   // ^128
  k_powmm<<<dim3(4, 4, 2), 256, 0, stream>>>(tA, tA, P256F, 65536, 65536, 65536, 1);// ^256
  k_castT<<<dim3(16, 37), 256, 0, stream>>>(slabF, Wi1, m0W, m1W, slabT, WtT);
  hipMemsetAsync(stats, 0, 8 * 512 * sizeof(float), stream);

  for (int blk = 0; blk < 4; ++blk) {
    const int pi = blk ? 1 : 0;
    const float* P16f = slabF + pi * SS + 15 * 65536;
    const float* P256f = P256F + pi * 65536;
    const ushort_t* slabTp = slabT + pi * SS;
    const float* mb = pi ? m1b : m0b;
    const float* msc = pi ? m1s : m0s;
    const float* mbi = pi ? m1bi : m0bi;

    if (blk == 0) {
      k_embed<<<NTOT, 256, 0, stream>>>(x, Wi0, bi0, u);
    } else {
      k_gemm<0><<<dim3(128, 2), 256, 0, stream>>>(h, WtT, bi1, u, nullptr);
    }

    // pass1 local scan via MFMA (h_local + E1 ends)
    k_scan_mfma<<<64, 256, 0, stream>>>(u, slabTp, h, e1);
    // hierarchical true-init computation (exact f32)
    k_scan<<<32, 512, 0, stream>>>(e1, P16f, nullptr, nullptr, e2, 16, 1);
    k_scan<<<4, 512, 0, stream>>>(e2, P256f, nullptr, t2, nullptr, 8, 1);
    k_scan<<<32, 512, 0, stream>>>(e1, P16f, t2, ee1, nullptr, 16, 8);
    // h += Init @ Wh^{j+1}  (batched over j)
    k_corr<<<dim3(8, 2, 16), 256, 0, stream>>>(ee1, slabTp, h);

    for (int l = 0; l < 2; ++l) {
      float* statsL = stats + (blk * 2 + l) * 512;
      const ushort_t* Wt = WtT + (1 + pi * 2 + l) * 65536;
      k_gemm<1><<<dim3(128, 2), 256, 0, stream>>>(h, Wt, mb + l * 256, u, statsL);
      k_bngelu<<<NTOT * DD / 1024, 256, 0, stream>>>(u, statsL, msc + l * 256,
                                                     mbi + l * 256, h);
    }
  }

  k_logits<<<256, 256, 0, stream>>>(h, Wr, br, (float*)d_out);
}

// Round 8
// 845.119 us; speedup vs baseline: 1.4826x; 1.0294x over previous
//
#include <hip/hip_runtime.h>
#include <hip/hip_bf16.h>

// LRUModel r7 (resubmit after infra timeout): fp16 storage for all big
// activations (u, h/H, y) — halves intermediate-tensor HBM traffic and removes
// f32->f16 cast VALU from GEMM staging. Small-scan hierarchy and stats stay f32.
// B=8,S=2048,D=256,V=6, 4 blocks of [linear-RNN scan -> 2x(Linear+BN+gelu+res)]

#define DD 256
#define NTOT 16384
#define L1C 16
#define EPSV 1e-5f

typedef unsigned short ushort_t;
typedef __attribute__((ext_vector_type(8))) unsigned short ushort8;
typedef __attribute__((ext_vector_type(8))) _Float16 f16x8;
typedef __attribute__((ext_vector_type(4))) float f32x4;

// ws layout (float offsets)
#define OFF_U     0L          // fp16 [16384][256] -> 2097152 floats
#define OFF_H     2097152L    // fp16 [16384][256]
#define OFF_E1    4194304L    // f32 1024*256
#define OFF_EE1   4456448L    // f32 1024*256
#define OFF_E2    4718592L    // f32 64*256
#define OFF_T2    4734976L    // f32 64*256
#define OFF_ST    4751360L    // f32 8*512
#define OFF_SLABF 4755456L    // f32 2*16*65536 (Wh^1..Wh^16)
#define OFF_P256F 6852608L    // f32 2*65536
#define OFF_TA    6983680L    // f32 2*65536
#define OFF_TB    7114752L    // f32 2*65536
#define OFF_SLABT 7245824L    // fp16 2*16*65536 -> 1048576 floats
#define OFF_WTT   8294400L    // fp16 5*65536 (Wi1,m0W0,m0W1,m1W0,m1W1 T)

__device__ __forceinline__ ushort_t hc(float f) {
  return __builtin_bit_cast(ushort_t, (_Float16)f);  // v_cvt_f16_f32 RNE
}
__device__ __forceinline__ float hf(ushort_t u) {
  return (float)__builtin_bit_cast(_Float16, u);
}

__device__ __forceinline__ f16x8 ldsf16(const ushort_t* p, int idx) {
  return __builtin_bit_cast(f16x8, *(const ushort8*)(p + idx));
}

__device__ __forceinline__ f32x4 mfma16h(f16x8 a, f16x8 b, f32x4 c) {
  return __builtin_amdgcn_mfma_f32_16x16x32_f16(a, b, c, 0, 0, 0);
}

__device__ __forceinline__ float gelu_fast(float x) {
  const float z = 0.7978845608028654f * (x + 0.044715f * x * x * x);
  return x / (1.f + __expf(-2.f * z));  // x * sigmoid(2z) == 0.5x(1+tanh z)
}

// ---------------- f32 64x64-tile GEMM (power-slab construction only) ---------
__device__ __forceinline__ void mm_tile(const float* __restrict__ A,
                                        const float* __restrict__ W,
                                        float* __restrict__ C) {
  __shared__ float As[16][68];
  __shared__ float Bs[16][68];
  const int tid = threadIdx.x;
  const int tx = tid & 15;
  const int ty = tid >> 4;
  const int bm = blockIdx.x * 64;
  const int bn = blockIdx.y * 64;
  float acc[4][4] = {};
  for (int k0 = 0; k0 < 256; k0 += 16) {
    {
      const int m = tid >> 2, ks = (tid & 3) * 4;
      const float4 av = *(const float4*)(A + (bm + m) * 256 + k0 + ks);
      As[ks + 0][m] = av.x; As[ks + 1][m] = av.y;
      As[ks + 2][m] = av.z; As[ks + 3][m] = av.w;
    }
    {
      const int kk = tid >> 4, n4 = (tid & 15) * 4;
      const float4 wv = *(const float4*)(W + (k0 + kk) * 256 + bn + n4);
      Bs[kk][n4 + 0] = wv.x; Bs[kk][n4 + 1] = wv.y;
      Bs[kk][n4 + 2] = wv.z; Bs[kk][n4 + 3] = wv.w;
    }
    __syncthreads();
#pragma unroll
    for (int kk = 0; kk < 16; ++kk) {
      const float a0 = As[kk][ty * 4 + 0];
      const float a1 = As[kk][ty * 4 + 1];
      const float a2 = As[kk][ty * 4 + 2];
      const float a3 = As[kk][ty * 4 + 3];
      const float4 b = *(const float4*)(&Bs[kk][tx * 4]);
      acc[0][0] = fmaf(a0, b.x, acc[0][0]); acc[0][1] = fmaf(a0, b.y, acc[0][1]);
      acc[0][2] = fmaf(a0, b.z, acc[0][2]); acc[0][3] = fmaf(a0, b.w, acc[0][3]);
      acc[1][0] = fmaf(a1, b.x, acc[1][0]); acc[1][1] = fmaf(a1, b.y, acc[1][1]);
      acc[1][2] = fmaf(a1, b.z, acc[1][2]); acc[1][3] = fmaf(a1, b.w, acc[1][3]);
      acc[2][0] = fmaf(a2, b.x, acc[2][0]); acc[2][1] = fmaf(a2, b.y, acc[2][1]);
      acc[2][2] = fmaf(a2, b.z, acc[2][2]); acc[2][3] = fmaf(a2, b.w, acc[2][3]);
      acc[3][0] = fmaf(a3, b.x, acc[3][0]); acc[3][1] = fmaf(a3, b.y, acc[3][1]);
      acc[3][2] = fmaf(a3, b.z, acc[3][2]); acc[3][3] = fmaf(a3, b.w, acc[3][3]);
    }
    __syncthreads();
  }
#pragma unroll
  for (int i = 0; i < 4; ++i) {
    float4 o;
    o.x = acc[i][0]; o.y = acc[i][1]; o.z = acc[i][2]; o.w = acc[i][3];
    *(float4*)(C + (bm + ty * 4 + i) * 256 + bn + tx * 4) = o;
  }
}

// batched power GEMM: z -> set=z/per, i=z%per; C[set,i] = A[set,i] @ B[set]
__global__ __launch_bounds__(256, 4) void k_powmm(const float* __restrict__ A,
                                                  const float* __restrict__ B,
                                                  float* __restrict__ C,
                                                  long sA, long sB, long sC, int per) {
  const int z = blockIdx.z;
  const int set = z / per, i = z % per;
  mm_tile(A + set * sA + (long)i * 65536, B + set * sB, C + set * sC + (long)i * 65536);
}

__global__ void k_copy2(const float* __restrict__ a, const float* __restrict__ b,
                        float* __restrict__ c0, float* __restrict__ c1) {
  const int i = (blockIdx.x * 256 + threadIdx.x) * 4;
  *(float4*)(c0 + i) = *(const float4*)(a + i);
  *(float4*)(c1 + i) = *(const float4*)(b + i);
}

// transpose+cast f32[256][256] -> fp16 out[n][k]; grid (16 tiles, 37 mats)
__global__ __launch_bounds__(256, 2) void k_castT(const float* __restrict__ slabF,
                                                  const float* __restrict__ Wi1,
                                                  const float* __restrict__ m0W,
                                                  const float* __restrict__ m1W,
                                                  ushort_t* __restrict__ slabT,
                                                  ushort_t* __restrict__ WtT) {
  const int mat = blockIdx.y;
  const float* src;
  ushort_t* dst;
  if (mat < 32)      { src = slabF + (long)mat * 65536;        dst = slabT + (long)mat * 65536; }
  else if (mat == 32){ src = Wi1;                              dst = WtT; }
  else if (mat < 35) { src = m0W + (long)(mat - 33) * 65536;   dst = WtT + (long)(mat - 32) * 65536; }
  else               { src = m1W + (long)(mat - 35) * 65536;   dst = WtT + (long)(mat - 32) * 65536; }
  const int rt = blockIdx.x >> 2, ct = blockIdx.x & 3;
  __shared__ float T[64][65];
  const int tid = threadIdx.x;
  {
    const int r = tid >> 2, cs = (tid & 3) * 16;
#pragma unroll
    for (int i = 0; i < 4; ++i) {
      const float4 v = *(const float4*)(src + (rt * 64 + r) * 256 + ct * 64 + cs + i * 4);
      T[r][cs + i * 4 + 0] = v.x; T[r][cs + i * 4 + 1] = v.y;
      T[r][cs + i * 4 + 2] = v.z; T[r][cs + i * 4 + 3] = v.w;
    }
  }
  __syncthreads();
  const int on = tid >> 2, ks = (tid & 3) * 16;
  ushort8 p0, p1;
#pragma unroll
  for (int i = 0; i < 8; ++i) p0[i] = hc(T[ks + i][on]);
#pragma unroll
  for (int i = 0; i < 8; ++i) p1[i] = hc(T[ks + 8 + i][on]);
  ushort_t* d = dst + (ct * 64 + on) * 256 + rt * 64 + ks;
  *(ushort8*)d = p0;
  *(ushort8*)(d + 8) = p1;
}

// ---------------- embedding (fp16 out) ----------------
__global__ void k_embed(const int* __restrict__ x, const float* __restrict__ Wi,
                        const float* __restrict__ bi, ushort_t* __restrict__ u) {
  const int n = blockIdx.x;
  const int d = threadIdx.x;
  const int t = x[n];
  u[(long)n * DD + d] = hc(Wi[t * DD + d] + bi[d]);
}

// ---------------- MFMA pass-1 scan (fp16 u in, fp16 H out, f32 E1) -----------
__global__ __launch_bounds__(256, 1) void k_scan_mfma(const ushort_t* __restrict__ u,
                                                      const ushort_t* __restrict__ Wt,
                                                      ushort_t* __restrict__ H,
                                                      float* __restrict__ E1) {
  __shared__ __align__(16) ushort_t hs[2][16 * 256];
  const int tid = threadIdx.x, lane = tid & 63, wave = tid >> 6;
  const int c0 = blockIdx.x * 16;
  const int arow = lane & 15;
  const int kgrp = lane >> 4;

  f16x8 bfrag[4][8];
#pragma unroll
  for (int nt = 0; nt < 4; ++nt) {
    const int col = wave * 64 + nt * 16 + arow;
#pragma unroll
    for (int kt = 0; kt < 8; ++kt) {
      const ushort8 p = *(const ushort8*)(Wt + col * 256 + kt * 32 + kgrp * 8);
      bfrag[nt][kt] = __builtin_bit_cast(f16x8, p);
    }
  }
  {
    ushort8 z;
#pragma unroll
    for (int q = 0; q < 8; ++q) z[q] = 0;
    *(ushort8*)&hs[0][tid * 8] = z;
    *(ushort8*)&hs[0][2048 + tid * 8] = z;
  }
  __syncthreads();

  int p = 0;
  for (int t = 0; t < L1C; ++t) {
    f16x8 afrag[8];
#pragma unroll
    for (int kt = 0; kt < 8; ++kt) {
      const int idx = arow * 256 + kt * 32 + kgrp * 8;
      afrag[kt] = ldsf16(hs[p], idx ^ ((arow & 7) << 3));
    }
#pragma unroll
    for (int nt = 0; nt < 4; ++nt) {
      f32x4 acc = {0.f, 0.f, 0.f, 0.f};
#pragma unroll
      for (int kt = 0; kt < 8; ++kt) acc = mfma16h(afrag[kt], bfrag[nt][kt], acc);
      const int col = wave * 64 + nt * 16 + arow;
#pragma unroll
      for (int i = 0; i < 4; ++i) {
        const int m = kgrp * 4 + i;  // chunk within block
        const long grow = (long)(c0 + m) * L1C + t;
        const float v = acc[i] + hf(u[grow * 256 + col]);
        const ushort_t v16 = hc(v);
        H[grow * 256 + col] = v16;
        const int idx = m * 256 + col;
        hs[p ^ 1][idx ^ ((m & 7) << 3)] = v16;
        if (t == L1C - 1) E1[(long)(c0 + m) * 256 + col] = v;
      }
    }
    __syncthreads();
    p ^= 1;
  }
}

// ---------------- f32 sequential chunk scan (small levels only) --------------
__global__ __launch_bounds__(512, 2) void k_scan(const float* __restrict__ u,
                                                 const float* __restrict__ W,
                                                 const float* __restrict__ Einit,
                                                 float* __restrict__ out_full,
                                                 float* __restrict__ out_ends,
                                                 int steps, int cper) {
  const int d = threadIdx.x & 255;
  const int half = threadIdx.x >> 8;
  const long r0 = (long)blockIdx.x * 2;
  __shared__ __align__(16) float hbuf[2][DD];
  __shared__ __align__(16) float psum[2][DD];

  float w[128];
  {
    const float* Wc = W + (long)(half * 128) * DD + d;
#pragma unroll
    for (int i = 0; i < 128; ++i) w[i] = Wc[(long)i * DD];
  }

  if (half == 0) {
#pragma unroll
    for (int g = 0; g < 2; ++g) {
      const long r = r0 + g;
      float hv = 0.f;
      if (Einit != nullptr && (int)(r % cper) != 0) hv = Einit[(r - 1) * DD + d];
      hbuf[g][d] = hv;
    }
  }
  __syncthreads();

  const float* __restrict__ ur0 = u + r0 * steps * DD + d;
  const float* __restrict__ ur1 = ur0 + (long)steps * DD;
  float* of0 = out_full ? out_full + r0 * steps * DD + d : nullptr;
  float* of1 = of0 ? of0 + (long)steps * DD : nullptr;
  const int e0 = half * 128;

  for (int t = 0; t < steps; ++t) {
    float uv0 = 0.f, uv1 = 0.f;
    if (half == 0) { uv0 = ur0[(long)t * DD]; uv1 = ur1[(long)t * DD]; }
    float a00 = 0.f, a01 = 0.f, a10 = 0.f, a11 = 0.f;
    const float4* hb0 = (const float4*)(&hbuf[0][e0]);
    const float4* hb1 = (const float4*)(&hbuf[1][e0]);
#pragma unroll
    for (int i = 0; i < 32; ++i) {
      const float4 h0 = hb0[i];
      const float4 h1 = hb1[i];
      a00 = fmaf(h0.x, w[4 * i + 0], a00);
      a01 = fmaf(h0.y, w[4 * i + 1], a01);
      a00 = fmaf(h0.z, w[4 * i + 2], a00);
      a01 = fmaf(h0.w, w[4 * i + 3], a01);
      a10 = fmaf(h1.x, w[4 * i + 0], a10);
      a11 = fmaf(h1.y, w[4 * i + 1], a11);
      a10 = fmaf(h1.z, w[4 * i + 2], a10);
      a11 = fmaf(h1.w, w[4 * i + 3], a11);
    }
    const float p0 = a00 + a01;
    const float p1 = a10 + a11;
    __syncthreads();
    if (half == 1) { psum[0][d] = p0; psum[1][d] = p1; }
    __syncthreads();
    if (half == 0) {
      const float n0 = p0 + psum[0][d] + uv0;
      const float n1 = p1 + psum[1][d] + uv1;
      hbuf[0][d] = n0; hbuf[1][d] = n1;
      if (of0) { of0[(long)t * DD] = n0; of1[(long)t * DD] = n1; }
    }
    __syncthreads();
  }
  if (out_ends != nullptr && half == 0) {
    out_ends[r0 * DD + d] = hbuf[0][d];
    out_ends[(r0 + 1) * DD + d] = hbuf[1][d];
  }
}

// ---------------- fp16 MFMA GEMM: C[M][256] = A[M][256] @ W + bias -----------
// A fp16 [M][256]; BT fp16 pre-transposed [n][k]; C fp16. STATS: fused col stats.
template <int STATS>
__global__ __launch_bounds__(256, 2) void k_gemm(const ushort_t* __restrict__ A,
                                                 const ushort_t* __restrict__ BT,
                                                 const float* __restrict__ bias,
                                                 ushort_t* __restrict__ C,
                                                 float* __restrict__ stats) {
  __shared__ __align__(16) ushort_t As[128 * 64];
  __shared__ __align__(16) ushort_t Bs[128 * 64];
  const int tid = threadIdx.x;
  const int lane = tid & 63;
  const int wave = tid >> 6;
  const int wr = wave >> 1, wc = wave & 1;
  const long m0 = (long)blockIdx.x * 128;
  const int n0 = blockIdx.y * 128;
  f32x4 acc[4][4];
#pragma unroll
  for (int i = 0; i < 4; ++i)
#pragma unroll
    for (int jn = 0; jn < 4; ++jn) acc[i][jn] = {0.f, 0.f, 0.f, 0.f};

  const int sr = tid >> 3;
  const int sk = (tid & 7) * 8;
#pragma unroll 1
  for (int kt = 0; kt < 4; ++kt) {
    const int kg = kt * 64;
#pragma unroll
    for (int it = 0; it < 4; ++it) {
      const int r = sr + it * 32;
      const ushort8 p = *(const ushort8*)(A + (m0 + r) * 256 + kg + sk);
      *(ushort8*)&As[(r * 64 + sk) ^ ((r & 7) << 3)] = p;
    }
#pragma unroll
    for (int it = 0; it < 4; ++it) {
      const int n = sr + it * 32;
      const ushort8 p = *(const ushort8*)(BT + (long)(n0 + n) * 256 + kg + sk);
      *(ushort8*)&Bs[(n * 64 + sk) ^ ((n & 7) << 3)] = p;
    }
    __syncthreads();
#pragma unroll
    for (int kk = 0; kk < 2; ++kk) {
      const int kb = kk * 32 + (lane >> 4) * 8;
      f16x8 af[4], bfr[4];
#pragma unroll
      for (int m = 0; m < 4; ++m) {
        const int row = wr * 64 + m * 16 + (lane & 15);
        af[m] = ldsf16(As, (row * 64 + kb) ^ ((row & 7) << 3));
      }
#pragma unroll
      for (int n = 0; n < 4; ++n) {
        const int col = wc * 64 + n * 16 + (lane & 15);
        bfr[n] = ldsf16(Bs, (col * 64 + kb) ^ ((col & 7) << 3));
      }
#pragma unroll
      for (int m = 0; m < 4; ++m)
#pragma unroll
        for (int n = 0; n < 4; ++n)
          acc[m][n] = mfma16h(af[m], bfr[n], acc[m][n]);
    }
    __syncthreads();
  }
  const int crow = (lane >> 4) * 4;
  const int ccol = lane & 15;
#pragma unroll
  for (int n = 0; n < 4; ++n) {
    const int col = n0 + wc * 64 + n * 16 + ccol;
    const float bv = bias[col];
    float cs = 0.f, cq = 0.f;
#pragma unroll
    for (int m = 0; m < 4; ++m) {
      const long rbase = m0 + wr * 64 + m * 16 + crow;
#pragma unroll
      for (int i = 0; i < 4; ++i) {
        const float v = acc[m][n][i] + bv;
        C[(rbase + i) * 256 + col] = hc(v);
        if (STATS) { cs += v; cq = fmaf(v, v, cq); }
      }
    }
    if (STATS) {
      cs += __shfl_xor(cs, 16); cq += __shfl_xor(cq, 16);
      cs += __shfl_xor(cs, 32); cq += __shfl_xor(cq, 32);
      if ((lane >> 4) == 0) {
        atomicAdd(&stats[col], cs);
        atomicAdd(&stats[256 + col], cq);
      }
    }
  }
}

// ---------------- correction: H[c*16+j] += Init[c] @ Wh^{j+1} (fp16 RMW) -----
__global__ __launch_bounds__(256, 2) void k_corr(const float* __restrict__ EE1,
                                                 const ushort_t* __restrict__ slabT,
                                                 ushort_t* __restrict__ H) {
  __shared__ __align__(16) ushort_t As[128 * 64];
  __shared__ __align__(16) ushort_t Bs[128 * 64];
  const int tid = threadIdx.x;
  const int lane = tid & 63;
  const int wave = tid >> 6;
  const int wr = wave >> 1, wc = wave & 1;
  const int m0 = blockIdx.x * 128;
  const int n0 = blockIdx.y * 128;
  const int j = blockIdx.z;
  const ushort_t* BT = slabT + (long)j * 65536;
  f32x4 acc[4][4];
#pragma unroll
  for (int i = 0; i < 4; ++i)
#pragma unroll
    for (int jn = 0; jn < 4; ++jn) acc[i][jn] = {0.f, 0.f, 0.f, 0.f};

  const int sr = tid >> 3;
  const int sk = (tid & 7) * 8;
#pragma unroll 1
  for (int kt = 0; kt < 4; ++kt) {
    const int kg = kt * 64;
#pragma unroll
    for (int it = 0; it < 4; ++it) {
      const int c = m0 + sr + it * 32;
      ushort8 p;
#pragma unroll
      for (int q = 0; q < 8; ++q) p[q] = 0;
      if ((c & 127) != 0) {
        const float* src = EE1 + (long)(c - 1) * 256 + kg + sk;
        const float4 f0 = *(const float4*)src;
        const float4 f1 = *(const float4*)(src + 4);
        p[0] = hc(f0.x); p[1] = hc(f0.y); p[2] = hc(f0.z); p[3] = hc(f0.w);
        p[4] = hc(f1.x); p[5] = hc(f1.y); p[6] = hc(f1.z); p[7] = hc(f1.w);
      }
      const int r = sr + it * 32;
      *(ushort8*)&As[(r * 64 + sk) ^ ((r & 7) << 3)] = p;
    }
#pragma unroll
    for (int it = 0; it < 4; ++it) {
      const int n = sr + it * 32;
      const ushort8 p = *(const ushort8*)(BT + (long)(n0 + n) * 256 + kg + sk);
      *(ushort8*)&Bs[(n * 64 + sk) ^ ((n & 7) << 3)] = p;
    }
    __syncthreads();
#pragma unroll
    for (int kk = 0; kk < 2; ++kk) {
      const int kb = kk * 32 + (lane >> 4) * 8;
      f16x8 af[4], bfr[4];
#pragma unroll
      for (int m = 0; m < 4; ++m) {
        const int row = wr * 64 + m * 16 + (lane & 15);
        af[m] = ldsf16(As, (row * 64 + kb) ^ ((row & 7) << 3));
      }
#pragma unroll
      for (int n = 0; n < 4; ++n) {
        const int col = wc * 64 + n * 16 + (lane & 15);
        bfr[n] = ldsf16(Bs, (col * 64 + kb) ^ ((col & 7) << 3));
      }
#pragma unroll
      for (int m = 0; m < 4; ++m)
#pragma unroll
        for (int n = 0; n < 4; ++n)
          acc[m][n] = mfma16h(af[m], bfr[n], acc[m][n]);
    }
    __syncthreads();
  }
  const int crow = (lane >> 4) * 4;
  const int ccol = lane & 15;
#pragma unroll
  for (int m = 0; m < 4; ++m) {
    const int cbase = m0 + wr * 64 + m * 16 + crow;
#pragma unroll
    for (int n = 0; n < 4; ++n) {
      const int col = n0 + wc * 64 + n * 16 + ccol;
#pragma unroll
      for (int i = 0; i < 4; ++i) {
        ushort_t* p = H + ((long)(cbase + i) * 16 + j) * 256 + col;
        *p = hc(hf(*p) + acc[m][n][i]);
      }
    }
  }
}

// ---------------- fused bn + gelu + residual (fp16 in/out, 8 elems/thread) ---
__global__ __launch_bounds__(256) void k_bngelu(const ushort_t* __restrict__ y,
                                                const float* __restrict__ stats,
                                                const float* __restrict__ scale,
                                                const float* __restrict__ bias,
                                                ushort_t* __restrict__ x) {
  const long i8 = ((long)blockIdx.x * 256 + threadIdx.x) * 8;
  const int d = (int)(i8 & 255);
  const ushort8 yv = *(const ushort8*)(y + i8);
  const ushort8 xv = *(const ushort8*)(x + i8);
  const float4 sm0 = *(const float4*)(stats + d);
  const float4 sm1 = *(const float4*)(stats + d + 4);
  const float4 sq0 = *(const float4*)(stats + DD + d);
  const float4 sq1 = *(const float4*)(stats + DD + d + 4);
  const float4 sc0 = *(const float4*)(scale + d);
  const float4 sc1 = *(const float4*)(scale + d + 4);
  const float4 bi0 = *(const float4*)(bias + d);
  const float4 bi1 = *(const float4*)(bias + d + 4);
  float sm[8] = {sm0.x, sm0.y, sm0.z, sm0.w, sm1.x, sm1.y, sm1.z, sm1.w};
  float sq[8] = {sq0.x, sq0.y, sq0.z, sq0.w, sq1.x, sq1.y, sq1.z, sq1.w};
  float sc[8] = {sc0.x, sc0.y, sc0.z, sc0.w, sc1.x, sc1.y, sc1.z, sc1.w};
  float bi[8] = {bi0.x, bi0.y, bi0.z, bi0.w, bi1.x, bi1.y, bi1.z, bi1.w};
  ushort8 o;
#pragma unroll
  for (int q = 0; q < 8; ++q) {
    const float mu = sm[q] * (1.f / NTOT);
    const float a = sc[q] * rsqrtf(sq[q] * (1.f / NTOT) - mu * mu + EPSV);
    o[q] = hc(gelu_fast((hf(yv[q]) - mu) * a + bi[q]) + hf(xv[q]));
  }
  *(ushort8*)(x + i8) = o;
}

// ---------------- logits via MFMA (N=6 padded to 16) -------------------------
__global__ __launch_bounds__(256, 2) void k_logits(const ushort_t* __restrict__ h,
                                                   const float* __restrict__ Wr,
                                                   const float* __restrict__ br,
                                                   float* __restrict__ out) {
  __shared__ __align__(16) ushort_t Hs[64 * 256];
  __shared__ __align__(16) ushort_t Ws[16 * 256];
  const int tid = threadIdx.x, lane = tid & 63, wave = tid >> 6;
  const long r0 = (long)blockIdx.x * 64;
  const int hr = tid >> 2;
#pragma unroll
  for (int it = 0; it < 8; ++it) {
    const int kq = (tid & 3) * 8 + it * 32;
    const ushort8 p = *(const ushort8*)(h + (r0 + hr) * 256 + kq);
    *(ushort8*)&Hs[(hr * 256 + kq) ^ ((hr & 7) << 3)] = p;
  }
  {
    float w6[6];
#pragma unroll
    for (int v = 0; v < 6; ++v) w6[v] = Wr[tid * 6 + v];
#pragma unroll
    for (int v = 0; v < 16; ++v)
      Ws[(v * 256 + tid) ^ ((v & 7) << 3)] = (v < 6) ? hc(w6[v]) : (ushort_t)0;
  }
  __syncthreads();
  f32x4 acc = {0.f, 0.f, 0.f, 0.f};
  const int arow = wave * 16 + (lane & 15);
  const int vcol = lane & 15;
#pragma unroll
  for (int kk = 0; kk < 8; ++kk) {
    const int kb = kk * 32 + (lane >> 4) * 8;
    const f16x8 a = ldsf16(Hs, (arow * 256 + kb) ^ ((arow & 7) << 3));
    const f16x8 b = ldsf16(Ws, (vcol * 256 + kb) ^ ((vcol & 7) << 3));
    acc = mfma16h(a, b, acc);
  }
  if (vcol < 6) {
    const float bv = br[vcol];
    const long rb = r0 + wave * 16 + (lane >> 4) * 4;
#pragma unroll
    for (int i = 0; i < 4; ++i) out[(rb + i) * 6 + vcol] = acc[i] + bv;
  }
}

extern "C" void kernel_launch(void* const* d_in, const int* in_sizes, int n_in,
                              void* d_out, int out_size, void* d_ws, size_t ws_size,
                              hipStream_t stream) {
  const int* x = (const int*)d_in[0];
  const float* Wi0 = (const float*)d_in[1];
  const float* bi0 = (const float*)d_in[2];
  const float* Wh0 = (const float*)d_in[3];
  const float* m0W = (const float*)d_in[4];
  const float* m0b = (const float*)d_in[5];
  const float* m0s = (const float*)d_in[6];
  const float* m0bi = (const float*)d_in[7];
  const float* Wi1 = (const float*)d_in[8];
  const float* bi1 = (const float*)d_in[9];
  const float* Wh1 = (const float*)d_in[10];
  const float* m1W = (const float*)d_in[11];
  const float* m1b = (const float*)d_in[12];
  const float* m1s = (const float*)d_in[13];
  const float* m1bi = (const float*)d_in[14];
  const float* Wr = (const float*)d_in[15];
  const float* br = (const float*)d_in[16];

  float* ws = (float*)d_ws;
  ushort_t* u = (ushort_t*)(ws + OFF_U);
  ushort_t* h = (ushort_t*)(ws + OFF_H);
  float* e1 = ws + OFF_E1;
  float* ee1 = ws + OFF_EE1;
  float* e2 = ws + OFF_E2;
  float* t2 = ws + OFF_T2;
  float* stats = ws + OFF_ST;
  float* slabF = ws + OFF_SLABF;
  float* P256F = ws + OFF_P256F;
  float* tA = ws + OFF_TA;
  float* tB = ws + OFF_TB;
  ushort_t* slabT = (ushort_t*)(ws + OFF_SLABT);
  ushort_t* WtT = (ushort_t*)(ws + OFF_WTT);
  const long SS = 16L * 65536;  // set stride (elements)

  // power slab: slab[i] = Wh^{i+1}, i=0..15, both param sets; P256 = Wh^256
  k_copy2<<<64, 256, 0, stream>>>(Wh0, Wh1, slabF, slabF + SS);
  k_powmm<<<dim3(4, 4, 2), 256, 0, stream>>>(slabF, slabF, slabF + 65536, SS, SS, SS, 1);
  k_powmm<<<dim3(4, 4, 4), 256, 0, stream>>>(slabF, slabF + 65536, slabF + 2 * 65536, SS, SS, SS, 2);
  k_powmm<<<dim3(4, 4, 8), 256, 0, stream>>>(slabF, slabF + 3 * 65536, slabF + 4 * 65536, SS, SS, SS, 4);
  k_powmm<<<dim3(4, 4, 16), 256, 0, stream>>>(slabF, slabF + 7 * 65536, slabF + 8 * 65536, SS, SS, SS, 8);
  k_powmm<<<dim3(4, 4, 2), 256, 0, stream>>>(slabF + 15 * 65536, slabF + 15 * 65536, tA, SS, SS, 65536, 1); // ^32
  k_powmm<<<dim3(4, 4, 2), 256, 0, stream>>>(tA, tA, tB, 65536, 65536, 65536, 1);   // ^64
  k_powmm<<<dim3(4, 4, 2), 256, 0, stream>>>(tB, tB, tA, 65536, 65536, 65536, 1);   // ^128
  k_powmm<<<dim3(4, 4, 2), 256, 0, stream>>>(tA, tA, P256F, 65536, 65536, 65536, 1);// ^256
  k_castT<<<dim3(16, 37), 256, 0, stream>>>(slabF, Wi1, m0W, m1W, slabT, WtT);
  hipMemsetAsync(stats, 0, 8 * 512 * sizeof(float), stream);

  for (int blk = 0; blk < 4; ++blk) {
    const int pi = blk ? 1 : 0;
    const float* P16f = slabF + pi * SS + 15 * 65536;
    const float* P256f = P256F + pi * 65536;
    const ushort_t* slabTp = slabT + pi * SS;
    const float* mb = pi ? m1b : m0b;
    const float* msc = pi ? m1s : m0s;
    const float* mbi = pi ? m1bi : m0bi;

    if (blk == 0) {
      k_embed<<<NTOT, 256, 0, stream>>>(x, Wi0, bi0, u);
    } else {
      k_gemm<0><<<dim3(128, 2), 256, 0, stream>>>(h, WtT, bi1, u, nullptr);
    }

    // pass1 local scan via MFMA (h_local fp16 + E1 ends f32)
    k_scan_mfma<<<64, 256, 0, stream>>>(u, slabTp, h, e1);
    // hierarchical true-init computation (exact f32)
    k_scan<<<32, 512, 0, stream>>>(e1, P16f, nullptr, nullptr, e2, 16, 1);
    k_scan<<<4, 512, 0, stream>>>(e2, P256f, nullptr, t2, nullptr, 8, 1);
    k_scan<<<32, 512, 0, stream>>>(e1, P16f, t2, ee1, nullptr, 16, 8);
    // h += Init @ Wh^{j+1}  (batched over j, fp16 RMW)
    k_corr<<<dim3(8, 2, 16), 256, 0, stream>>>(ee1, slabTp, h);

    for (int l = 0; l < 2; ++l) {
      float* statsL = stats + (blk * 2 + l) * 512;
      const ushort_t* Wt = WtT + (1 + pi * 2 + l) * 65536;
      k_gemm<1><<<dim3(128, 2), 256, 0, stream>>>(h, Wt, mb + l * 256, u, statsL);
      k_bngelu<<<NTOT * DD / 2048, 256, 0, stream>>>(u, statsL, msc + l * 256,
                                                     mbi + l * 256, h);
    }
  }

  k_logits<<<256, 256, 0, stream>>>(h, Wr, br, (float*)d_out);
}